// Round 9
// baseline (233.239 us; speedup 1.0000x reference)
//
#include <hip/hip_runtime.h>

#define NQ     12
#define NPARAM 240       // 12*4*5
#define BLOCK  512
#define NREG   8

// Storage position p for a qubit:
//   p in [0,3)  -> register bit p of r (st[8]/lane)     : pure VALU
//   p in [3,5)  -> lane bit (p-3), DPP quad_perm        : pure VALU
//   p in [5,9)  -> lane bit (p-3), shfl (ds_bpermute)   : LDS pipe (avoid for gates)
//   p in [9,12) -> tid bit (p-3) = wave bit             : select-only for ctrl
// QMAP[m][p] = qubit at position p under map m. Gate TARGETS at positions 0..4.
//
// R9: halved remap buffer (16 KB, e[11] two-phase protocol) to cut the LDS
// block footprint 37.9K -> ~20.9K and test the 2-blocks/CU residency theory
// (OccupancyPercent pinned at exactly 50% in R8 despite 4 blocks fitting).

constexpr int QMAP[5][12] = {
    // pos:   0   1   2   3   4    5   6   7   8    9  10  11
    /*M0*/ {  0,  1,  2,  3,  4,  10, 11,  9,  8,   5,  6,  7},
    /*M1*/ {  5,  6,  7,  8,  9,   3,  4, 10, 11,   0,  1,  2},
    /*M2*/ { 10, 11,  0,  9,  8,   3,  4,  5,  6,   1,  2,  7},
    /*M3*/ {  7,  6,  5,  4,  3,   9,  8, 10, 11,   0,  1,  2},
    /*M4*/ {  2,  1,  0, 11,  4,   3,  9,  8, 10,   5,  6,  7},
};

constexpr int posof(int m, int q) {
    for (int p = 0; p < 12; ++p) if (QMAP[m][p] == q) return p;
    return -1;
}
// linear buf index e = (r_old << 9) | tid_old : old pos p -> e bit
constexpr int ebit(int p) { return p < 3 ? 9 + p : p - 3; }
// compile-time read offset contribution of new register index r (MA -> MB)
constexpr int roff(int MA, int MB, int r) {
    int off = 0;
    for (int p = 0; p < 3; ++p)
        off |= ((r >> p) & 1) << ebit(posof(MA, QMAP[MB][p]));
    return off;
}

template<int MA, int MB>
__device__ __forceinline__ int rbase(int tid) {
    int base = 0;
    #pragma unroll
    for (int p = 3; p < 12; ++p)
        base |= ((tid >> (p - 3)) & 1) << ebit(posof(MA, QMAP[MB][p]));
    return base;
}

// Two-phase remap, wave-predicate flavor (old pos-2 qubit -> wave bit in MB:
// read-index bit 11 comes from base only, wave-uniform). Phase 1 serves
// e[11]=0 readers (old regs 0..3), phase 2 serves e[11]=1 (old regs 4..7).
template<int MA, int MB>
__device__ __forceinline__ void remap_w(float2* st, int tid, float2* buf, int base) {
    const bool first = ((base >> 11) & 1) == 0;   // wave-uniform
    const int b11 = base & 2047;
    __syncthreads();                               // WAR vs prior buf readers
    #pragma unroll
    for (int r = 0; r < 4; ++r) buf[r * BLOCK + tid] = st[r];
    __syncthreads();
    float2 t4 = st[4], t5 = st[5], t6 = st[6], t7 = st[7];
    if (first) {
        #pragma unroll
        for (int r = 0; r < NREG; ++r) st[r] = buf[(b11 + roff(MA, MB, r)) & 2047];
    }
    __syncthreads();
    buf[0 * BLOCK + tid] = t4; buf[1 * BLOCK + tid] = t5;
    buf[2 * BLOCK + tid] = t6; buf[3 * BLOCK + tid] = t7;
    __syncthreads();
    if (!first) {
        #pragma unroll
        for (int r = 0; r < NREG; ++r) st[r] = buf[(b11 + roff(MA, MB, r)) & 2047];
    }
}

// Two-phase remap, register-predicate flavor (M4->M0: read bit 11 = r'&1,
// compile-time). Even new regs read in phase 1 (into temps), odd in phase 2.
template<int MA, int MB>
__device__ __forceinline__ void remap_r(float2* st, int tid, float2* buf, int base) {
    __syncthreads();
    #pragma unroll
    for (int r = 0; r < 4; ++r) buf[r * BLOCK + tid] = st[r];
    __syncthreads();
    float2 te[4];
    #pragma unroll
    for (int k = 0; k < 4; ++k)
        te[k] = buf[base + (roff(MA, MB, 2 * k) & 2047)];
    __syncthreads();
    #pragma unroll
    for (int r = 0; r < 4; ++r) buf[r * BLOCK + tid] = st[4 + r];
    __syncthreads();
    #pragma unroll
    for (int k = 0; k < 4; ++k)
        st[2 * k + 1] = buf[base + (roff(MA, MB, 2 * k + 1) & 2047)];
    #pragma unroll
    for (int k = 0; k < 4; ++k) st[2 * k] = te[k];
}

template<int LM>
__device__ __forceinline__ float lxor(float v) {
    if constexpr (LM == 1) {        // quad_perm [1,0,3,2] = xor 1, VALU pipe
        return __int_as_float(__builtin_amdgcn_update_dpp(
            __float_as_int(v), __float_as_int(v), 0xB1, 0xF, 0xF, false));
    } else if constexpr (LM == 2) { // quad_perm [2,3,0,1] = xor 2, VALU pipe
        return __int_as_float(__builtin_amdgcn_update_dpp(
            __float_as_int(v), __float_as_int(v), 0x4E, 0xF, 0xF, false));
    } else {
        return __shfl_xor(v, LM, 64);
    }
}

__device__ __forceinline__ float2 cmulf(float2 a, float2 b) {
    return make_float2(a.x*b.x - a.y*b.y, a.x*b.y + a.y*b.x);
}

// plain 1q gate at position P (used only for U(q0) at pos 0)
template<int P>
__device__ __forceinline__ void apply1q(float2* st, int tid, const float* m) {
    float u00x=m[0],u00y=m[1],u01x=m[2],u01y=m[3];
    float u10x=m[4],u10y=m[5],u11x=m[6],u11y=m[7];
    if constexpr (P < 3) {
        #pragma unroll
        for (int r = 0; r < NREG; ++r) {
            if ((r >> P) & 1) continue;
            int r1 = r | (1 << P);
            float2 s0 = st[r], s1 = st[r1];
            st[r]  = make_float2(u00x*s0.x - u00y*s0.y + u01x*s1.x - u01y*s1.y,
                                 u00x*s0.y + u00y*s0.x + u01x*s1.y + u01y*s1.x);
            st[r1] = make_float2(u10x*s0.x - u10y*s0.y + u11x*s1.x - u11y*s1.y,
                                 u10x*s0.y + u10y*s0.x + u11x*s1.y + u11y*s1.x);
        }
    } else {
        constexpr int LM = 1 << (P - 3);
        int bit = (tid >> (P - 3)) & 1;
        float dx = bit ? u11x : u00x, dy = bit ? u11y : u00y;
        float ox = bit ? u10x : u01x, oy = bit ? u10y : u01y;
        #pragma unroll
        for (int r = 0; r < NREG; ++r) {
            float sx = st[r].x, sy = st[r].y;
            float px = lxor<LM>(sx), py = lxor<LM>(sy);
            st[r] = make_float2(dx*sx - dy*sy + ox*px - oy*py,
                                dx*sy + dy*sx + ox*py + oy*px);
        }
    }
}

// fused ring1 gate: ctrl at PC, tgt at PT. Applies A (ctrl=0) / B (ctrl=1),
// where A = U(tgt), B = RX(theta)*U(tgt). PT always < 5 by schedule.
template<int PC, int PT>
__device__ __forceinline__ void fgate(float2* st, int tid,
                                      const float* A, const float* B) {
    if constexpr (PT < 3) {
        if constexpr (PC < 3) {
            #pragma unroll
            for (int r = 0; r < NREG; ++r) {
                if ((r >> PT) & 1) continue;
                const float* M = ((r >> PC) & 1) ? B : A;   // compile-time
                float m00x=M[0],m00y=M[1],m01x=M[2],m01y=M[3];
                float m10x=M[4],m10y=M[5],m11x=M[6],m11y=M[7];
                int r1 = r | (1 << PT);
                float2 s0 = st[r], s1 = st[r1];
                st[r]  = make_float2(m00x*s0.x - m00y*s0.y + m01x*s1.x - m01y*s1.y,
                                     m00x*s0.y + m00y*s0.x + m01x*s1.y + m01y*s1.x);
                st[r1] = make_float2(m10x*s0.x - m10y*s0.y + m11x*s1.x - m11y*s1.y,
                                     m10x*s0.y + m10y*s0.x + m11x*s1.y + m11y*s1.x);
            }
        } else {
            int cbit = (tid >> (PC - 3)) & 1;
            float m00x = cbit ? B[0] : A[0], m00y = cbit ? B[1] : A[1];
            float m01x = cbit ? B[2] : A[2], m01y = cbit ? B[3] : A[3];
            float m10x = cbit ? B[4] : A[4], m10y = cbit ? B[5] : A[5];
            float m11x = cbit ? B[6] : A[6], m11y = cbit ? B[7] : A[7];
            #pragma unroll
            for (int r = 0; r < NREG; ++r) {
                if ((r >> PT) & 1) continue;
                int r1 = r | (1 << PT);
                float2 s0 = st[r], s1 = st[r1];
                st[r]  = make_float2(m00x*s0.x - m00y*s0.y + m01x*s1.x - m01y*s1.y,
                                     m00x*s0.y + m00y*s0.x + m01x*s1.y + m01y*s1.x);
                st[r1] = make_float2(m10x*s0.x - m10y*s0.y + m11x*s1.x - m11y*s1.y,
                                     m10x*s0.y + m10y*s0.x + m11x*s1.y + m11y*s1.x);
            }
        }
    } else {
        constexpr int LM = 1 << (PT - 3);
        int tbit = (tid >> (PT - 3)) & 1;
        float dAx = tbit ? A[6] : A[0], dAy = tbit ? A[7] : A[1];
        float oAx = tbit ? A[4] : A[2], oAy = tbit ? A[5] : A[3];
        float dBx = tbit ? B[6] : B[0], dBy = tbit ? B[7] : B[1];
        float oBx = tbit ? B[4] : B[2], oBy = tbit ? B[5] : B[3];
        if constexpr (PC < 3) {
            #pragma unroll
            for (int r = 0; r < NREG; ++r) {
                const bool uB = (r >> PC) & 1;               // compile-time
                float dx = uB ? dBx : dAx, dy = uB ? dBy : dAy;
                float ox = uB ? oBx : oAx, oy = uB ? oBy : oAy;
                float sx = st[r].x, sy = st[r].y;
                float px = lxor<LM>(sx), py = lxor<LM>(sy);
                st[r] = make_float2(dx*sx - dy*sy + ox*px - oy*py,
                                    dx*sy + dy*sx + ox*py + oy*px);
            }
        } else {
            int cbit = (tid >> (PC - 3)) & 1;
            float dx = cbit ? dBx : dAx, dy = cbit ? dBy : dAy;
            float ox = cbit ? oBx : oAx, oy = cbit ? oBy : oAy;
            #pragma unroll
            for (int r = 0; r < NREG; ++r) {
                float sx = st[r].x, sy = st[r].y;
                float px = lxor<LM>(sx), py = lxor<LM>(sy);
                st[r] = make_float2(dx*sx - dy*sy + ox*px - oy*py,
                                    dx*sy + dy*sx + ox*py + oy*px);
            }
        }
    }
}

// CRX(ctrl at PC, tgt at PT<5): on ctrl=1 apply RX: n = c*self - i*s*other
template<int PC, int PT>
__device__ __forceinline__ void applyCRX(float2* st, int tid, const float* cs) {
    float c = cs[0], s = cs[1];
    if constexpr (PT < 3) {
        if constexpr (PC < 3) {
            #pragma unroll
            for (int r = 0; r < NREG; ++r) {
                if (!((r >> PC) & 1) || ((r >> PT) & 1)) continue;
                int r1 = r | (1 << PT);
                float2 s0 = st[r], s1 = st[r1];
                st[r]  = make_float2(c*s0.x + s*s1.y, c*s0.y - s*s1.x);
                st[r1] = make_float2(c*s1.x + s*s0.y, c*s1.y - s*s0.x);
            }
        } else {
            int apply = (tid >> (PC - 3)) & 1;
            float cc = apply ? c : 1.0f, ss = apply ? s : 0.0f;
            #pragma unroll
            for (int r = 0; r < NREG; ++r) {
                if ((r >> PT) & 1) continue;
                int r1 = r | (1 << PT);
                float2 s0 = st[r], s1 = st[r1];
                st[r]  = make_float2(cc*s0.x + ss*s1.y, cc*s0.y - ss*s1.x);
                st[r1] = make_float2(cc*s1.x + ss*s0.y, cc*s1.y - ss*s0.x);
            }
        }
    } else {
        constexpr int LM = 1 << (PT - 3);
        if constexpr (PC < 3) {
            #pragma unroll
            for (int r = 0; r < NREG; ++r) {
                if (!((r >> PC) & 1)) continue;
                float sx = st[r].x, sy = st[r].y;
                float px = lxor<LM>(sx), py = lxor<LM>(sy);
                st[r] = make_float2(c*sx + s*py, c*sy - s*px);
            }
        } else {
            int apply = (tid >> (PC - 3)) & 1;
            float cc = apply ? c : 1.0f, ss = apply ? s : 0.0f;
            #pragma unroll
            for (int r = 0; r < NREG; ++r) {
                float sx = st[r].x, sy = st[r].y;
                float px = lxor<LM>(sx), py = lxor<LM>(sy);
                st[r] = make_float2(cc*sx + ss*py, cc*sy - ss*px);
            }
        }
    }
}

template<int P>
__device__ __forceinline__ void expectq(const float2* st, int tid, float2* buf,
                                        float& X, float& Y, float& Z) {
    float lx = 0.f, ly = 0.f, lz = 0.f;
    if constexpr (P < 3) {
        #pragma unroll
        for (int r = 0; r < NREG; ++r) {
            float2 a = st[r];
            float n = a.x*a.x + a.y*a.y;
            lz += ((r >> P) & 1) ? -n : n;
        }
        #pragma unroll
        for (int r = 0; r < NREG; ++r) {
            if ((r >> P) & 1) continue;
            int r1 = r | (1 << P);
            float2 s0 = st[r], s1 = st[r1];
            lx += s0.x*s1.x + s0.y*s1.y;
            ly += s0.x*s1.y - s0.y*s1.x;
        }
    } else if constexpr (P < 9) {
        constexpr int LM = 1 << (P - 3);
        int bit = (tid >> (P - 3)) & 1;
        float zs = bit ? -1.f : 1.f;
        float m  = bit ?  0.f : 1.f;
        #pragma unroll
        for (int r = 0; r < NREG; ++r) {
            float2 a = st[r];
            lz += zs * (a.x*a.x + a.y*a.y);
            float px = lxor<LM>(a.x), py = lxor<LM>(a.y);
            lx += m * (a.x*px + a.y*py);
            ly += m * (a.x*py - a.y*px);
        }
    } else {
        constexpr int XM = 1 << (P - 3);
        int bit = (tid >> (P - 3)) & 1;
        float zs = bit ? -1.f : 1.f;
        float m  = bit ?  0.f : 1.f;
        int pt = tid ^ XM;
        __syncthreads();
        #pragma unroll
        for (int r = 0; r < 4; ++r) buf[r * BLOCK + tid] = st[r];
        __syncthreads();
        #pragma unroll
        for (int r = 0; r < 4; ++r) {
            float2 a = st[r];
            lz += zs * (a.x*a.x + a.y*a.y);
            float2 o = buf[r * BLOCK + pt];
            lx += m * (a.x*o.x + a.y*o.y);
            ly += m * (a.x*o.y - a.y*o.x);
        }
        __syncthreads();
        #pragma unroll
        for (int r = 0; r < 4; ++r) buf[r * BLOCK + tid] = st[4 + r];
        __syncthreads();
        #pragma unroll
        for (int r = 0; r < 4; ++r) {
            float2 a = st[4 + r];
            lz += zs * (a.x*a.x + a.y*a.y);
            float2 o = buf[r * BLOCK + pt];
            lx += m * (a.x*o.x + a.y*o.y);
            ly += m * (a.x*o.y - a.y*o.x);
        }
    }
    #pragma unroll
    for (int off = 32; off; off >>= 1) {
        lx += __shfl_xor(lx, off, 64);
        ly += __shfl_xor(ly, off, 64);
        lz += __shfl_xor(lz, off, 64);
    }
    X = 2.f*lx; Y = 2.f*ly; Z = lz;
}

__global__ __launch_bounds__(BLOCK)
void qfe_kernel(const float* __restrict__ params,
                const float* __restrict__ inputs,
                float* __restrict__ out) {
    const int b    = blockIdx.x;
    const int tid  = threadIdx.x;
    const int lane = tid & 63;
    const int w    = tid >> 6;

    __shared__ float2 buf[4 * BLOCK];      // 16 KB half remap buffer (e[11] phased)
    __shared__ float  mA[4 * 12 * 8];      // U = Rz*Ry*Rx (*RYembed at l=0)
    __shared__ float  mB[4 * 11 * 8];      // B = RX(ring1_j) * U(j+1), j=0..10
    __shared__ float  mcrx[4 * 24 * 2];    // (cos,sin) ring1 j=0..11, ring2 12..23
    __shared__ float  redbuf[8][36];

    if (tid < 48) {
        int l = tid / 12, q = tid % 12;
        const float* pp = params + b * NPARAM + l * 60 + q * 3;
        float ax = pp[0]*0.5f, ay = pp[1]*0.5f, az = pp[2]*0.5f;
        float cx = cosf(ax), sx = sinf(ax);
        float cy = cosf(ay), sy = sinf(ay);
        float cz = cosf(az), sz = sinf(az);
        float2 a00 = make_float2( cy*cx,  sy*sx);
        float2 a01 = make_float2(-sy*cx, -cy*sx);
        float2 a10 = make_float2( sy*cx, -cy*sx);
        float2 a11 = make_float2( cy*cx, -sy*sx);
        float2 e0 = make_float2(cz, -sz);
        float2 e1 = make_float2(cz,  sz);
        float2 u00 = cmulf(e0, a00), u01 = cmulf(e0, a01);
        float2 u10 = cmulf(e1, a10), u11 = cmulf(e1, a11);
        if (l == 0) {   // fold RY input embedding
            float e = inputs[b * NQ + q] * 0.5f;
            float ce = cosf(e), se = sinf(e);
            float2 v00 = make_float2(u00.x*ce + u01.x*se, u00.y*ce + u01.y*se);
            float2 v01 = make_float2(-u00.x*se + u01.x*ce, -u00.y*se + u01.y*ce);
            float2 v10 = make_float2(u10.x*ce + u11.x*se, u10.y*ce + u11.y*se);
            float2 v11 = make_float2(-u10.x*se + u11.x*ce, -u10.y*se + u11.y*ce);
            u00 = v00; u01 = v01; u10 = v10; u11 = v11;
        }
        float* m = &mA[(l * 12 + q) * 8];
        m[0]=u00.x; m[1]=u00.y; m[2]=u01.x; m[3]=u01.y;
        m[4]=u10.x; m[5]=u10.y; m[6]=u11.x; m[7]=u11.y;
    }
    if (tid < 96) {
        int l = tid / 24, k = tid % 24;
        float a = params[b * NPARAM + l * 60 + 36 + k] * 0.5f;
        mcrx[(l * 24 + k) * 2]     = cosf(a);
        mcrx[(l * 24 + k) * 2 + 1] = sinf(a);
    }
    __syncthreads();
    if (tid < 44) {       // B(l,j) = RX(theta_ring1_j) * U(l, j+1)
        int l = tid / 11, j = tid % 11;
        const float* U = mA + (l * 12 + (j + 1)) * 8;
        float c = mcrx[(l * 24 + j) * 2], s = mcrx[(l * 24 + j) * 2 + 1];
        float* Bm = mB + (l * 11 + j) * 8;
        Bm[0] =  c*U[0] + s*U[5];
        Bm[1] =  c*U[1] - s*U[4];
        Bm[2] =  c*U[2] + s*U[7];
        Bm[3] =  c*U[3] - s*U[6];
        Bm[4] =  s*U[1] + c*U[4];
        Bm[5] = -s*U[0] + c*U[5];
        Bm[6] =  s*U[3] + c*U[6];
        Bm[7] = -s*U[2] + c*U[7];
    }
    __syncthreads();

    float2 st[NREG];
    #pragma unroll
    for (int r = 0; r < NREG; ++r) st[r] = make_float2(0.f, 0.f);
    if (tid == 0) st[0] = make_float2(1.f, 0.f);

    // remap read bases (depend only on tid) — hoisted out of the layer loop
    const int rb1 = rbase<0,1>(tid);
    const int rb2 = rbase<1,2>(tid);
    const int rb3 = rbase<2,3>(tid);
    const int rb4 = rbase<3,4>(tid);
    const int rb0 = rbase<4,0>(tid);

    #pragma unroll 1
    for (int l = 0; l < 4; ++l) {
        const float* ma = mA + l * 96;
        const float* mb = mB + l * 88;
        const float* cl = mcrx + l * 48;
        // --- M0: q0@0,q1@1,q2@2,q3@3,q4@4 ---
        apply1q<0>(st, tid, ma + 0 * 8);               // U(q0)
        fgate<0, 1>(st, tid, ma + 1 * 8, mb + 0 * 8);  // F(0,1)
        fgate<1, 2>(st, tid, ma + 2 * 8, mb + 1 * 8);  // F(1,2)
        fgate<2, 3>(st, tid, ma + 3 * 8, mb + 2 * 8);  // F(2,3)
        fgate<3, 4>(st, tid, ma + 4 * 8, mb + 3 * 8);  // F(3,4)
        remap_w<0, 1>(st, tid, buf, rb1);
        // --- M1: q5@0,q6@1,q7@2,q8@3,q9@4; q4@6 ---
        fgate<6, 0>(st, tid, ma + 5 * 8, mb + 4 * 8);  // F(4,5)
        fgate<0, 1>(st, tid, ma + 6 * 8, mb + 5 * 8);  // F(5,6)
        fgate<1, 2>(st, tid, ma + 7 * 8, mb + 6 * 8);  // F(6,7)
        fgate<2, 3>(st, tid, ma + 8 * 8, mb + 7 * 8);  // F(7,8)
        fgate<3, 4>(st, tid, ma + 9 * 8, mb + 8 * 8);  // F(8,9)
        remap_w<1, 2>(st, tid, buf, rb2);
        // --- M2: q10@0,q11@1,q0@2,q9@3,q8@4 ---
        fgate<3, 0>(st, tid, ma + 10 * 8, mb + 9 * 8);  // F(9,10)
        fgate<0, 1>(st, tid, ma + 11 * 8, mb + 10 * 8); // F(10,11)
        applyCRX<1, 2>(st, tid, cl + 11 * 2);           // CRX(11,0) plain
        applyCRX<1, 0>(st, tid, cl + 12 * 2);           // ring2 (11,10)
        applyCRX<0, 3>(st, tid, cl + 13 * 2);           // (10,9)
        applyCRX<3, 4>(st, tid, cl + 14 * 2);           // (9,8)
        remap_w<2, 3>(st, tid, buf, rb3);
        // --- M3: q7@0,q6@1,q5@2,q4@3,q3@4; q8@6 ---
        applyCRX<6, 0>(st, tid, cl + 15 * 2);           // (8,7)
        applyCRX<0, 1>(st, tid, cl + 16 * 2);           // (7,6)
        applyCRX<1, 2>(st, tid, cl + 17 * 2);           // (6,5)
        applyCRX<2, 3>(st, tid, cl + 18 * 2);           // (5,4)
        applyCRX<3, 4>(st, tid, cl + 19 * 2);           // (4,3)
        remap_w<3, 4>(st, tid, buf, rb4);
        // --- M4: q2@0,q1@1,q0@2,q11@3; q3@5 ---
        applyCRX<5, 0>(st, tid, cl + 20 * 2);           // (3,2)
        applyCRX<0, 1>(st, tid, cl + 21 * 2);           // (2,1)
        applyCRX<1, 2>(st, tid, cl + 22 * 2);           // (1,0)
        applyCRX<2, 3>(st, tid, cl + 23 * 2);           // (0,11)
        remap_r<4, 0>(st, tid, buf, rb0);
    }

    // Expectations under M0: qubit -> position
    // 0..4 -> 0..4, 5->9, 6->10, 7->11, 8->8, 9->7, 10->5, 11->6
#define EXPECT(q, P) { float X, Y, Z; expectq<P>(st, tid, buf, X, Y, Z); \
                       if (lane == 0) { redbuf[w][(q)] = X; redbuf[w][12 + (q)] = Y; redbuf[w][24 + (q)] = Z; } }
    EXPECT(0, 0)  EXPECT(1, 1)  EXPECT(2, 2)  EXPECT(3, 3)
    EXPECT(4, 4)  EXPECT(5, 9)  EXPECT(6, 10) EXPECT(7, 11)
    EXPECT(8, 8)  EXPECT(9, 7)  EXPECT(10, 5) EXPECT(11, 6)
    __syncthreads();
    if (tid < 36) {
        float acc = 0.f;
        #pragma unroll
        for (int i = 0; i < 8; ++i) acc += redbuf[i][tid];
        out[b * 36 + tid] = acc;
    }
}

extern "C" void kernel_launch(void* const* d_in, const int* in_sizes, int n_in,
                              void* d_out, int out_size, void* d_ws, size_t ws_size,
                              hipStream_t stream) {
    const float* params = (const float*)d_in[0];   // (1024, 240) float32
    const float* inputs = (const float*)d_in[1];   // (1024, 12)  float32
    float* out = (float*)d_out;                    // (1024, 36)  float32
    qfe_kernel<<<1024, BLOCK, 0, stream>>>(params, inputs, out);
}

// Round 10
// 127.793 us; speedup vs baseline: 1.8251x; 1.8251x over previous
//
#include <hip/hip_runtime.h>

#define NQ     12
#define NPARAM 240       // 12*4*5
#define BLOCK  512
#define NREG   8

// Storage position p for a qubit:
//   p in [0,3)  -> register bit p of r (st[8]/lane)     : pure VALU
//   p in [3,5)  -> lane bit (p-3), DPP quad_perm        : pure VALU
//   p in [5,9)  -> lane bit (p-3), shfl/buf             : LDS pipe (avoid for gates)
//   p in [9,12) -> tid bit (p-3) = wave bit             : select-only for ctrl
// QMAP[m][p] = qubit at position p under map m. Gate TARGETS at positions 0..4.
//
// LDS bank rule (R8/R10 lesson): wave64 b64 accesses are processed in fixed
// 16-lane quarters; bank-pair bits e[3:0] must be a bijection of tid[3:0]
// within each quarter. The swizzle e ^= (e>>2)&0xC (bits 2,3 ^= bits 4,5)
// makes all five remap-read patterns below quarter-bijective (verified per
// transition) while keeping writes (consecutive tid) conflict-free.

constexpr int QMAP[5][12] = {
    // pos:   0   1   2   3   4    5   6   7   8    9  10  11
    /*M0*/ {  0,  1,  2,  3,  4,  10, 11,  9,  8,   5,  6,  7},
    /*M1*/ {  5,  6,  7,  8,  9,   3,  4, 10, 11,   0,  1,  2},
    /*M2*/ { 10, 11,  0,  9,  8,   3,  4,  5,  6,   1,  2,  7},
    /*M3*/ {  7,  6,  5,  4,  3,   9,  8, 10, 11,   0,  1,  2},
    /*M4*/ {  2,  1,  0, 11,  4,   3,  9,  8, 10,   5,  6,  7},
};

constexpr int posof(int m, int q) {
    for (int p = 0; p < 12; ++p) if (QMAP[m][p] == q) return p;
    return -1;
}
// linear buf index e = (r_old << 9) | tid_old : old pos p -> e bit
constexpr int ebit(int p) { return p < 3 ? 9 + p : p - 3; }
// compile-time read offset contribution of new register index r (MA -> MB)
constexpr int roff(int MA, int MB, int r) {
    int off = 0;
    for (int p = 0; p < 3; ++p)
        off |= ((r >> p) & 1) << ebit(posof(MA, QMAP[MB][p]));
    return off;
}
constexpr int cswz(int x) { return x ^ ((x & 0x30) >> 2); }

template<int MA, int MB>
__device__ __forceinline__ int rbase(int tid) {
    int base = 0;
    #pragma unroll
    for (int p = 3; p < 12; ++p)
        base |= ((tid >> (p - 3)) & 1) << ebit(posof(MA, QMAP[MB][p]));
    return base;
}

// swizzled-layout remap: write at swz(e) via wtid; read swz(base|roff) =
// swz(base) ^ cswz(roff)  (base/roff occupy disjoint bits; XOR is linear)
template<int MA, int MB>
__device__ __forceinline__ void remap(float2* st, int wtid, float2* buf, int sbase) {
    __syncthreads();                       // WAR vs prior buf readers
    #pragma unroll
    for (int r = 0; r < NREG; ++r) buf[r * BLOCK + wtid] = st[r];
    __syncthreads();
    #pragma unroll
    for (int r = 0; r < NREG; ++r) st[r] = buf[sbase ^ cswz(roff(MA, MB, r))];
}

template<int LM>
__device__ __forceinline__ float lxor(float v) {
    if constexpr (LM == 1) {        // quad_perm [1,0,3,2] = xor 1, VALU pipe
        return __int_as_float(__builtin_amdgcn_update_dpp(
            __float_as_int(v), __float_as_int(v), 0xB1, 0xF, 0xF, false));
    } else if constexpr (LM == 2) { // quad_perm [2,3,0,1] = xor 2, VALU pipe
        return __int_as_float(__builtin_amdgcn_update_dpp(
            __float_as_int(v), __float_as_int(v), 0x4E, 0xF, 0xF, false));
    } else {
        return __shfl_xor(v, LM, 64);
    }
}

// DPP wave-64 sum: row_shr 1/2/4/8 then bcast15/bcast31; total lands in lane 63
__device__ __forceinline__ float wsum(float x) {
    x += __int_as_float(__builtin_amdgcn_update_dpp(0, __float_as_int(x), 0x111, 0xF, 0xF, true));
    x += __int_as_float(__builtin_amdgcn_update_dpp(0, __float_as_int(x), 0x112, 0xF, 0xF, true));
    x += __int_as_float(__builtin_amdgcn_update_dpp(0, __float_as_int(x), 0x114, 0xF, 0xF, true));
    x += __int_as_float(__builtin_amdgcn_update_dpp(0, __float_as_int(x), 0x118, 0xF, 0xF, true));
    x += __int_as_float(__builtin_amdgcn_update_dpp(0, __float_as_int(x), 0x142, 0xa, 0xF, false));
    x += __int_as_float(__builtin_amdgcn_update_dpp(0, __float_as_int(x), 0x143, 0xc, 0xF, false));
    return x;
}

__device__ __forceinline__ float2 cmulf(float2 a, float2 b) {
    return make_float2(a.x*b.x - a.y*b.y, a.x*b.y + a.y*b.x);
}

// plain 1q gate at position P (used only for U(q0) at pos 0)
template<int P>
__device__ __forceinline__ void apply1q(float2* st, int tid, const float* m) {
    float u00x=m[0],u00y=m[1],u01x=m[2],u01y=m[3];
    float u10x=m[4],u10y=m[5],u11x=m[6],u11y=m[7];
    if constexpr (P < 3) {
        #pragma unroll
        for (int r = 0; r < NREG; ++r) {
            if ((r >> P) & 1) continue;
            int r1 = r | (1 << P);
            float2 s0 = st[r], s1 = st[r1];
            st[r]  = make_float2(u00x*s0.x - u00y*s0.y + u01x*s1.x - u01y*s1.y,
                                 u00x*s0.y + u00y*s0.x + u01x*s1.y + u01y*s1.x);
            st[r1] = make_float2(u10x*s0.x - u10y*s0.y + u11x*s1.x - u11y*s1.y,
                                 u10x*s0.y + u10y*s0.x + u11x*s1.y + u11y*s1.x);
        }
    } else {
        constexpr int LM = 1 << (P - 3);
        int bit = (tid >> (P - 3)) & 1;
        float dx = bit ? u11x : u00x, dy = bit ? u11y : u00y;
        float ox = bit ? u10x : u01x, oy = bit ? u10y : u01y;
        #pragma unroll
        for (int r = 0; r < NREG; ++r) {
            float sx = st[r].x, sy = st[r].y;
            float px = lxor<LM>(sx), py = lxor<LM>(sy);
            st[r] = make_float2(dx*sx - dy*sy + ox*px - oy*py,
                                dx*sy + dy*sx + ox*py + oy*px);
        }
    }
}

// fused ring1 gate: ctrl at PC, tgt at PT. Applies A (ctrl=0) / B (ctrl=1),
// where A = U(tgt), B = RX(theta)*U(tgt). PT always < 5 by schedule.
template<int PC, int PT>
__device__ __forceinline__ void fgate(float2* st, int tid,
                                      const float* A, const float* B) {
    if constexpr (PT < 3) {
        if constexpr (PC < 3) {
            #pragma unroll
            for (int r = 0; r < NREG; ++r) {
                if ((r >> PT) & 1) continue;
                const float* M = ((r >> PC) & 1) ? B : A;   // compile-time
                float m00x=M[0],m00y=M[1],m01x=M[2],m01y=M[3];
                float m10x=M[4],m10y=M[5],m11x=M[6],m11y=M[7];
                int r1 = r | (1 << PT);
                float2 s0 = st[r], s1 = st[r1];
                st[r]  = make_float2(m00x*s0.x - m00y*s0.y + m01x*s1.x - m01y*s1.y,
                                     m00x*s0.y + m00y*s0.x + m01x*s1.y + m01y*s1.x);
                st[r1] = make_float2(m10x*s0.x - m10y*s0.y + m11x*s1.x - m11y*s1.y,
                                     m10x*s0.y + m10y*s0.x + m11x*s1.y + m11y*s1.x);
            }
        } else {
            int cbit = (tid >> (PC - 3)) & 1;
            float m00x = cbit ? B[0] : A[0], m00y = cbit ? B[1] : A[1];
            float m01x = cbit ? B[2] : A[2], m01y = cbit ? B[3] : A[3];
            float m10x = cbit ? B[4] : A[4], m10y = cbit ? B[5] : A[5];
            float m11x = cbit ? B[6] : A[6], m11y = cbit ? B[7] : A[7];
            #pragma unroll
            for (int r = 0; r < NREG; ++r) {
                if ((r >> PT) & 1) continue;
                int r1 = r | (1 << PT);
                float2 s0 = st[r], s1 = st[r1];
                st[r]  = make_float2(m00x*s0.x - m00y*s0.y + m01x*s1.x - m01y*s1.y,
                                     m00x*s0.y + m00y*s0.x + m01x*s1.y + m01y*s1.x);
                st[r1] = make_float2(m10x*s0.x - m10y*s0.y + m11x*s1.x - m11y*s1.y,
                                     m10x*s0.y + m10y*s0.x + m11x*s1.y + m11y*s1.x);
            }
        }
    } else {
        constexpr int LM = 1 << (PT - 3);
        int tbit = (tid >> (PT - 3)) & 1;
        float dAx = tbit ? A[6] : A[0], dAy = tbit ? A[7] : A[1];
        float oAx = tbit ? A[4] : A[2], oAy = tbit ? A[5] : A[3];
        float dBx = tbit ? B[6] : B[0], dBy = tbit ? B[7] : B[1];
        float oBx = tbit ? B[4] : B[2], oBy = tbit ? B[5] : B[3];
        if constexpr (PC < 3) {
            #pragma unroll
            for (int r = 0; r < NREG; ++r) {
                const bool uB = (r >> PC) & 1;               // compile-time
                float dx = uB ? dBx : dAx, dy = uB ? dBy : dAy;
                float ox = uB ? oBx : oAx, oy = uB ? oBy : oAy;
                float sx = st[r].x, sy = st[r].y;
                float px = lxor<LM>(sx), py = lxor<LM>(sy);
                st[r] = make_float2(dx*sx - dy*sy + ox*px - oy*py,
                                    dx*sy + dy*sx + ox*py + oy*px);
            }
        } else {
            int cbit = (tid >> (PC - 3)) & 1;
            float dx = cbit ? dBx : dAx, dy = cbit ? dBy : dAy;
            float ox = cbit ? oBx : oAx, oy = cbit ? oBy : oAy;
            #pragma unroll
            for (int r = 0; r < NREG; ++r) {
                float sx = st[r].x, sy = st[r].y;
                float px = lxor<LM>(sx), py = lxor<LM>(sy);
                st[r] = make_float2(dx*sx - dy*sy + ox*px - oy*py,
                                    dx*sy + dy*sx + ox*py + oy*px);
            }
        }
    }
}

// CRX(ctrl at PC, tgt at PT<5): on ctrl=1 apply RX: n = c*self - i*s*other
template<int PC, int PT>
__device__ __forceinline__ void applyCRX(float2* st, int tid, const float* cs) {
    float c = cs[0], s = cs[1];
    if constexpr (PT < 3) {
        if constexpr (PC < 3) {
            #pragma unroll
            for (int r = 0; r < NREG; ++r) {
                if (!((r >> PC) & 1) || ((r >> PT) & 1)) continue;
                int r1 = r | (1 << PT);
                float2 s0 = st[r], s1 = st[r1];
                st[r]  = make_float2(c*s0.x + s*s1.y, c*s0.y - s*s1.x);
                st[r1] = make_float2(c*s1.x + s*s0.y, c*s1.y - s*s0.x);
            }
        } else {
            int apply = (tid >> (PC - 3)) & 1;
            float cc = apply ? c : 1.0f, ss = apply ? s : 0.0f;
            #pragma unroll
            for (int r = 0; r < NREG; ++r) {
                if ((r >> PT) & 1) continue;
                int r1 = r | (1 << PT);
                float2 s0 = st[r], s1 = st[r1];
                st[r]  = make_float2(cc*s0.x + ss*s1.y, cc*s0.y - ss*s1.x);
                st[r1] = make_float2(cc*s1.x + ss*s0.y, cc*s1.y - ss*s0.x);
            }
        }
    } else {
        constexpr int LM = 1 << (PT - 3);
        if constexpr (PC < 3) {
            #pragma unroll
            for (int r = 0; r < NREG; ++r) {
                if (!((r >> PC) & 1)) continue;
                float sx = st[r].x, sy = st[r].y;
                float px = lxor<LM>(sx), py = lxor<LM>(sy);
                st[r] = make_float2(c*sx + s*py, c*sy - s*px);
            }
        } else {
            int apply = (tid >> (PC - 3)) & 1;
            float cc = apply ? c : 1.0f, ss = apply ? s : 0.0f;
            #pragma unroll
            for (int r = 0; r < NREG; ++r) {
                float sx = st[r].x, sy = st[r].y;
                float px = lxor<LM>(sx), py = lxor<LM>(sy);
                st[r] = make_float2(cc*sx + ss*py, cc*sy - ss*px);
            }
        }
    }
}

__global__ __launch_bounds__(BLOCK)
void qfe_kernel(const float* __restrict__ params,
                const float* __restrict__ inputs,
                float* __restrict__ out) {
    const int b    = blockIdx.x;
    const int tid  = threadIdx.x;
    const int lane = tid & 63;
    const int w    = tid >> 6;

    __shared__ float2 buf[NREG * BLOCK];   // 32 KB remap/exchange buffer
    __shared__ float  mA[4 * 12 * 8];      // U = Rz*Ry*Rx (*RYembed at l=0)
    __shared__ float  mB[4 * 11 * 8];      // B = RX(ring1_j) * U(j+1), j=0..10
    __shared__ float  mcrx[4 * 24 * 2];    // (cos,sin) ring1 j=0..11, ring2 12..23
    __shared__ float  redbuf[8][36];

    if (tid < 48) {
        int l = tid / 12, q = tid % 12;
        const float* pp = params + b * NPARAM + l * 60 + q * 3;
        float ax = pp[0]*0.5f, ay = pp[1]*0.5f, az = pp[2]*0.5f;
        float cx = cosf(ax), sx = sinf(ax);
        float cy = cosf(ay), sy = sinf(ay);
        float cz = cosf(az), sz = sinf(az);
        float2 a00 = make_float2( cy*cx,  sy*sx);
        float2 a01 = make_float2(-sy*cx, -cy*sx);
        float2 a10 = make_float2( sy*cx, -cy*sx);
        float2 a11 = make_float2( cy*cx, -sy*sx);
        float2 e0 = make_float2(cz, -sz);
        float2 e1 = make_float2(cz,  sz);
        float2 u00 = cmulf(e0, a00), u01 = cmulf(e0, a01);
        float2 u10 = cmulf(e1, a10), u11 = cmulf(e1, a11);
        if (l == 0) {   // fold RY input embedding
            float e = inputs[b * NQ + q] * 0.5f;
            float ce = cosf(e), se = sinf(e);
            float2 v00 = make_float2(u00.x*ce + u01.x*se, u00.y*ce + u01.y*se);
            float2 v01 = make_float2(-u00.x*se + u01.x*ce, -u00.y*se + u01.y*ce);
            float2 v10 = make_float2(u10.x*ce + u11.x*se, u10.y*ce + u11.y*se);
            float2 v11 = make_float2(-u10.x*se + u11.x*ce, -u10.y*se + u11.y*ce);
            u00 = v00; u01 = v01; u10 = v10; u11 = v11;
        }
        float* m = &mA[(l * 12 + q) * 8];
        m[0]=u00.x; m[1]=u00.y; m[2]=u01.x; m[3]=u01.y;
        m[4]=u10.x; m[5]=u10.y; m[6]=u11.x; m[7]=u11.y;
    }
    if (tid < 96) {
        int l = tid / 24, k = tid % 24;
        float a = params[b * NPARAM + l * 60 + 36 + k] * 0.5f;
        mcrx[(l * 24 + k) * 2]     = cosf(a);
        mcrx[(l * 24 + k) * 2 + 1] = sinf(a);
    }
    __syncthreads();
    if (tid < 44) {       // B(l,j) = RX(theta_ring1_j) * U(l, j+1)
        int l = tid / 11, j = tid % 11;
        const float* U = mA + (l * 12 + (j + 1)) * 8;
        float c = mcrx[(l * 24 + j) * 2], s = mcrx[(l * 24 + j) * 2 + 1];
        float* Bm = mB + (l * 11 + j) * 8;
        Bm[0] =  c*U[0] + s*U[5];
        Bm[1] =  c*U[1] - s*U[4];
        Bm[2] =  c*U[2] + s*U[7];
        Bm[3] =  c*U[3] - s*U[6];
        Bm[4] =  s*U[1] + c*U[4];
        Bm[5] = -s*U[0] + c*U[5];
        Bm[6] =  s*U[3] + c*U[6];
        Bm[7] = -s*U[2] + c*U[7];
    }
    __syncthreads();

    float2 st[NREG];
    #pragma unroll
    for (int r = 0; r < NREG; ++r) st[r] = make_float2(0.f, 0.f);
    if (tid == 0) st[0] = make_float2(1.f, 0.f);

    // swizzled write tid + swizzled remap read bases (hoisted; layer-invariant)
    const int wtid = tid ^ ((tid & 0x30) >> 2);
    const int rb1 = rbase<0,1>(tid); const int sb1 = rb1 ^ ((rb1 & 0x30) >> 2);
    const int rb2 = rbase<1,2>(tid); const int sb2 = rb2 ^ ((rb2 & 0x30) >> 2);
    const int rb3 = rbase<2,3>(tid); const int sb3 = rb3 ^ ((rb3 & 0x30) >> 2);
    const int rb4 = rbase<3,4>(tid); const int sb4 = rb4 ^ ((rb4 & 0x30) >> 2);
    const int rb0 = rbase<4,0>(tid); const int sb0 = rb0 ^ ((rb0 & 0x30) >> 2);

    #pragma unroll 1
    for (int l = 0; l < 4; ++l) {
        const float* ma = mA + l * 96;
        const float* mb = mB + l * 88;
        const float* cl = mcrx + l * 48;
        // --- M0: q0@0,q1@1,q2@2,q3@3,q4@4 ---
        apply1q<0>(st, tid, ma + 0 * 8);               // U(q0)
        fgate<0, 1>(st, tid, ma + 1 * 8, mb + 0 * 8);  // F(0,1)
        fgate<1, 2>(st, tid, ma + 2 * 8, mb + 1 * 8);  // F(1,2)
        fgate<2, 3>(st, tid, ma + 3 * 8, mb + 2 * 8);  // F(2,3)
        fgate<3, 4>(st, tid, ma + 4 * 8, mb + 3 * 8);  // F(3,4)
        remap<0, 1>(st, wtid, buf, sb1);
        // --- M1: q5@0,q6@1,q7@2,q8@3,q9@4; q4@6 ---
        fgate<6, 0>(st, tid, ma + 5 * 8, mb + 4 * 8);  // F(4,5)
        fgate<0, 1>(st, tid, ma + 6 * 8, mb + 5 * 8);  // F(5,6)
        fgate<1, 2>(st, tid, ma + 7 * 8, mb + 6 * 8);  // F(6,7)
        fgate<2, 3>(st, tid, ma + 8 * 8, mb + 7 * 8);  // F(7,8)
        fgate<3, 4>(st, tid, ma + 9 * 8, mb + 8 * 8);  // F(8,9)
        remap<1, 2>(st, wtid, buf, sb2);
        // --- M2: q10@0,q11@1,q0@2,q9@3,q8@4 ---
        fgate<3, 0>(st, tid, ma + 10 * 8, mb + 9 * 8);  // F(9,10)
        fgate<0, 1>(st, tid, ma + 11 * 8, mb + 10 * 8); // F(10,11)
        applyCRX<1, 2>(st, tid, cl + 11 * 2);           // CRX(11,0) plain
        applyCRX<1, 0>(st, tid, cl + 12 * 2);           // ring2 (11,10)
        applyCRX<0, 3>(st, tid, cl + 13 * 2);           // (10,9)
        applyCRX<3, 4>(st, tid, cl + 14 * 2);           // (9,8)
        remap<2, 3>(st, wtid, buf, sb3);
        // --- M3: q7@0,q6@1,q5@2,q4@3,q3@4; q8@6 ---
        applyCRX<6, 0>(st, tid, cl + 15 * 2);           // (8,7)
        applyCRX<0, 1>(st, tid, cl + 16 * 2);           // (7,6)
        applyCRX<1, 2>(st, tid, cl + 17 * 2);           // (6,5)
        applyCRX<2, 3>(st, tid, cl + 18 * 2);           // (5,4)
        applyCRX<3, 4>(st, tid, cl + 19 * 2);           // (4,3)
        remap<3, 4>(st, wtid, buf, sb4);
        // --- M4: q2@0,q1@1,q0@2,q11@3; q3@5 ---
        applyCRX<5, 0>(st, tid, cl + 20 * 2);           // (3,2)
        applyCRX<0, 1>(st, tid, cl + 21 * 2);           // (2,1)
        applyCRX<1, 2>(st, tid, cl + 22 * 2);           // (1,0)
        applyCRX<2, 3>(st, tid, cl + 23 * 2);           // (0,11)
        remap<4, 0>(st, wtid, buf, sb0);
    }

    // ---- epilogue: expectations under M0 ----
    // q0,q1,q2 = reg bits 0,1,2 ; q3,q4 = tid bits 0,1 (DPP xor1/xor2) ;
    // q10,q11,q9,q8 = tid bits 2,3,4,5 ; q5,q6,q7 = tid bits 6,7,8 (buf partner)
    float nn[NREG];
    #pragma unroll
    for (int r = 0; r < NREG; ++r) nn[r] = st[r].x*st[r].x + st[r].y*st[r].y;
    float T  = ((nn[0]+nn[1])+(nn[2]+nn[3])) + ((nn[4]+nn[5])+(nn[6]+nn[7]));
    float Z0 = ((nn[0]-nn[1])+(nn[2]-nn[3])) + ((nn[4]-nn[5])+(nn[6]-nn[7]));
    float Z1 = ((nn[0]+nn[1])-(nn[2]+nn[3])) + ((nn[4]+nn[5])-(nn[6]+nn[7]));
    float Z2 = ((nn[0]+nn[1])+(nn[2]+nn[3])) - ((nn[4]+nn[5])+(nn[6]+nn[7]));

    __syncthreads();                       // WAR vs last remap reads
    #pragma unroll
    for (int r = 0; r < NREG; ++r) buf[r * BLOCK + tid] = st[r];   // plain layout
    __syncthreads();

    // reg-bit qubits: sum over in-lane pairs, 2x at the end
#define EXP_REG(q, B, ZV) { \
    float lx = 0.f, ly = 0.f; \
    _Pragma("unroll") \
    for (int r = 0; r < NREG; ++r) { \
        if ((r >> (B)) & 1) continue; \
        int r1 = r | (1 << (B)); \
        lx += st[r].x*st[r1].x + st[r].y*st[r1].y; \
        ly += st[r].x*st[r1].y - st[r].y*st[r1].x; \
    } \
    float X = wsum(2.f*lx), Y = wsum(2.f*ly), Z = wsum(ZV); \
    if (lane == 63) { redbuf[w][(q)] = X; redbuf[w][12+(q)] = Y; redbuf[w][24+(q)] = Z; } }

    // lane/wave qubits: both sides summed (conj symmetry -> no 2x, sign on Im)
#define EXP_DPP(q, LM, TB) { \
    float lx = 0.f, lyr = 0.f; \
    _Pragma("unroll") \
    for (int r = 0; r < NREG; ++r) { \
        float px = lxor<LM>(st[r].x), py = lxor<LM>(st[r].y); \
        lx  += st[r].x*px + st[r].y*py; \
        lyr += st[r].x*py - st[r].y*px; \
    } \
    float zs = ((tid >> (TB)) & 1) ? -1.f : 1.f; \
    float X = wsum(lx), Y = wsum(zs*lyr), Z = wsum(zs*T); \
    if (lane == 63) { redbuf[w][(q)] = X; redbuf[w][12+(q)] = Y; redbuf[w][24+(q)] = Z; } }

#define EXP_BUF(q, XM, TB) { \
    float lx = 0.f, lyr = 0.f; \
    int pt = tid ^ (XM); \
    _Pragma("unroll") \
    for (int r = 0; r < NREG; ++r) { \
        float2 p = buf[r * BLOCK + pt]; \
        lx  += st[r].x*p.x + st[r].y*p.y; \
        lyr += st[r].x*p.y - st[r].y*p.x; \
    } \
    float zs = ((tid >> (TB)) & 1) ? -1.f : 1.f; \
    float X = wsum(lx), Y = wsum(zs*lyr), Z = wsum(zs*T); \
    if (lane == 63) { redbuf[w][(q)] = X; redbuf[w][12+(q)] = Y; redbuf[w][24+(q)] = Z; } }

    EXP_REG(0, 0, Z0)  EXP_REG(1, 1, Z1)  EXP_REG(2, 2, Z2)
    EXP_DPP(3, 1, 0)   EXP_DPP(4, 2, 1)
    EXP_BUF(10, 4, 2)  EXP_BUF(11, 8, 3)  EXP_BUF(9, 16, 4)  EXP_BUF(8, 32, 5)
    EXP_BUF(5, 64, 6)  EXP_BUF(6, 128, 7) EXP_BUF(7, 256, 8)

    __syncthreads();
    if (tid < 36) {
        float acc = 0.f;
        #pragma unroll
        for (int i = 0; i < 8; ++i) acc += redbuf[i][tid];
        out[b * 36 + tid] = acc;
    }
}

extern "C" void kernel_launch(void* const* d_in, const int* in_sizes, int n_in,
                              void* d_out, int out_size, void* d_ws, size_t ws_size,
                              hipStream_t stream) {
    const float* params = (const float*)d_in[0];   // (1024, 240) float32
    const float* inputs = (const float*)d_in[1];   // (1024, 12)  float32
    float* out = (float*)d_out;                    // (1024, 36)  float32
    qfe_kernel<<<1024, BLOCK, 0, stream>>>(params, inputs, out);
}

// Round 11
// 124.395 us; speedup vs baseline: 1.8750x; 1.0273x over previous
//
#include <hip/hip_runtime.h>

#define NQ     12
#define NPARAM 240       // 12*4*5
#define BLOCK  512
#define NREG   8

typedef float v2f __attribute__((ext_vector_type(2)));

// ---- packed complex primitives (v_pk_*_f32, VOP3P, full-rate on CDNA4) ----
// complex t = a(.)b : lo = ax*bx - ay*by ; hi = ax*by + ay*bx
__device__ __forceinline__ v2f pk_cmul(v2f a, v2f b) {
    v2f t;
    asm("v_pk_mul_f32 %0, %1, %2 op_sel:[0,0] op_sel_hi:[0,1]\n\t"
        "v_pk_fma_f32 %0, %1, %2, %0 op_sel:[1,1,0] op_sel_hi:[1,0,1] neg_lo:[1,0,0]"
        : "=&v"(t) : "v"(a), "v"(b));
    return t;
}
// complex t += a(.)b
__device__ __forceinline__ v2f pk_cmac(v2f t0, v2f a, v2f b) {
    v2f t;
    asm("v_pk_fma_f32 %0, %2, %3, %1 op_sel:[0,0,0] op_sel_hi:[0,1,1]\n\t"
        "v_pk_fma_f32 %0, %2, %3, %0 op_sel:[1,1,0] op_sel_hi:[1,0,1] neg_lo:[1,0,0]"
        : "=&v"(t) : "v"(t0), "v"(a), "v"(b));
    return t;
}
// CRX halfstep: t = cc*s - i*ss*p, cs2=(cc,ss): lo = cc*sx + ss*py ; hi = cc*sy - ss*px
__device__ __forceinline__ v2f pk_crx(v2f cs2, v2f s, v2f p) {
    v2f t;
    asm("v_pk_mul_f32 %0, %1, %2 op_sel:[0,0] op_sel_hi:[0,1]\n\t"
        "v_pk_fma_f32 %0, %1, %3, %0 op_sel:[1,1,0] op_sel_hi:[1,0,1] neg_hi:[0,1,0]"
        : "=&v"(t) : "v"(cs2), "v"(s), "v"(p));
    return t;
}
// conj-accumulate: acc += conj(s)(.)p : lo += sx*px + sy*py ; hi += sx*py - sy*px
__device__ __forceinline__ v2f pk_cjmac(v2f a0, v2f s, v2f p) {
    v2f t;
    asm("v_pk_fma_f32 %0, %2, %3, %1 op_sel:[0,0,0] op_sel_hi:[0,1,1]\n\t"
        "v_pk_fma_f32 %0, %2, %3, %0 op_sel:[1,1,0] op_sel_hi:[1,0,1] neg_hi:[1,0,0]"
        : "=&v"(t) : "v"(a0), "v"(s), "v"(p));
    return t;
}
#define M2(m, i) (((const v2f*)(m))[i])

// Storage position p for a qubit (unchanged from R10):
//   p in [0,3)  -> register bit p of r       : pure VALU
//   p in [3,5)  -> lane bit (p-3), DPP       : pure VALU
//   p in [5,9)  -> lane bit (p-3), shfl/buf  : LDS pipe (avoid for gates)
//   p in [9,12) -> tid bit (p-3) = wave bit  : select-only for ctrl
// LDS bank rule (R10, verified): swizzle e ^= (e>>2)&0xC makes remap reads
// quarter-bijective -> conflicts ~0.

constexpr int QMAP[5][12] = {
    // pos:   0   1   2   3   4    5   6   7   8    9  10  11
    /*M0*/ {  0,  1,  2,  3,  4,  10, 11,  9,  8,   5,  6,  7},
    /*M1*/ {  5,  6,  7,  8,  9,   3,  4, 10, 11,   0,  1,  2},
    /*M2*/ { 10, 11,  0,  9,  8,   3,  4,  5,  6,   1,  2,  7},
    /*M3*/ {  7,  6,  5,  4,  3,   9,  8, 10, 11,   0,  1,  2},
    /*M4*/ {  2,  1,  0, 11,  4,   3,  9,  8, 10,   5,  6,  7},
};

constexpr int posof(int m, int q) {
    for (int p = 0; p < 12; ++p) if (QMAP[m][p] == q) return p;
    return -1;
}
constexpr int ebit(int p) { return p < 3 ? 9 + p : p - 3; }
constexpr int roff(int MA, int MB, int r) {
    int off = 0;
    for (int p = 0; p < 3; ++p)
        off |= ((r >> p) & 1) << ebit(posof(MA, QMAP[MB][p]));
    return off;
}
constexpr int cswz(int x) { return x ^ ((x & 0x30) >> 2); }

template<int MA, int MB>
__device__ __forceinline__ int rbase(int tid) {
    int base = 0;
    #pragma unroll
    for (int p = 3; p < 12; ++p)
        base |= ((tid >> (p - 3)) & 1) << ebit(posof(MA, QMAP[MB][p]));
    return base;
}

template<int MA, int MB>
__device__ __forceinline__ void remap(v2f* st, int wtid, v2f* buf, int sbase) {
    __syncthreads();                       // WAR vs prior buf readers
    #pragma unroll
    for (int r = 0; r < NREG; ++r) buf[r * BLOCK + wtid] = st[r];
    __syncthreads();
    #pragma unroll
    for (int r = 0; r < NREG; ++r) st[r] = buf[sbase ^ cswz(roff(MA, MB, r))];
}

template<int LM>
__device__ __forceinline__ float lxor(float v) {
    if constexpr (LM == 1) {
        return __int_as_float(__builtin_amdgcn_update_dpp(
            __float_as_int(v), __float_as_int(v), 0xB1, 0xF, 0xF, false));
    } else if constexpr (LM == 2) {
        return __int_as_float(__builtin_amdgcn_update_dpp(
            __float_as_int(v), __float_as_int(v), 0x4E, 0xF, 0xF, false));
    } else {
        return __shfl_xor(v, LM, 64);
    }
}
template<int LM>
__device__ __forceinline__ v2f lxor2(v2f v) {
    v2f p = { lxor<LM>(v.x), lxor<LM>(v.y) };
    return p;
}

// DPP wave-64 sum; total lands in lane 63
__device__ __forceinline__ float wsum(float x) {
    x += __int_as_float(__builtin_amdgcn_update_dpp(0, __float_as_int(x), 0x111, 0xF, 0xF, true));
    x += __int_as_float(__builtin_amdgcn_update_dpp(0, __float_as_int(x), 0x112, 0xF, 0xF, true));
    x += __int_as_float(__builtin_amdgcn_update_dpp(0, __float_as_int(x), 0x114, 0xF, 0xF, true));
    x += __int_as_float(__builtin_amdgcn_update_dpp(0, __float_as_int(x), 0x118, 0xF, 0xF, true));
    x += __int_as_float(__builtin_amdgcn_update_dpp(0, __float_as_int(x), 0x142, 0xa, 0xF, false));
    x += __int_as_float(__builtin_amdgcn_update_dpp(0, __float_as_int(x), 0x143, 0xc, 0xF, false));
    return x;
}

__device__ __forceinline__ float2 cmulf(float2 a, float2 b) {
    return make_float2(a.x*b.x - a.y*b.y, a.x*b.y + a.y*b.x);
}

// plain 1q gate at position P
template<int P>
__device__ __forceinline__ void apply1q(v2f* st, int tid, const float* m) {
    v2f u00 = M2(m,0), u01 = M2(m,1), u10 = M2(m,2), u11 = M2(m,3);
    if constexpr (P < 3) {
        #pragma unroll
        for (int r = 0; r < NREG; ++r) {
            if ((r >> P) & 1) continue;
            int r1 = r | (1 << P);
            v2f s0 = st[r], s1 = st[r1];
            st[r]  = pk_cmac(pk_cmul(u00, s0), u01, s1);
            st[r1] = pk_cmac(pk_cmul(u10, s0), u11, s1);
        }
    } else {
        constexpr int LM = 1 << (P - 3);
        int bit = (tid >> (P - 3)) & 1;
        v2f d = bit ? u11 : u00;
        v2f o = bit ? u10 : u01;
        #pragma unroll
        for (int r = 0; r < NREG; ++r) {
            v2f p = lxor2<LM>(st[r]);
            st[r] = pk_cmac(pk_cmul(d, st[r]), o, p);
        }
    }
}

// fused ring1 gate: A (ctrl=0) / B = RX*A (ctrl=1); PT < 5 by schedule
template<int PC, int PT>
__device__ __forceinline__ void fgate(v2f* st, int tid,
                                      const float* A, const float* B) {
    v2f a00 = M2(A,0), a01 = M2(A,1), a10 = M2(A,2), a11 = M2(A,3);
    v2f b00 = M2(B,0), b01 = M2(B,1), b10 = M2(B,2), b11 = M2(B,3);
    if constexpr (PT < 3) {
        if constexpr (PC < 3) {
            #pragma unroll
            for (int r = 0; r < NREG; ++r) {
                if ((r >> PT) & 1) continue;
                const bool uB = (r >> PC) & 1;               // compile-time
                v2f m00 = uB ? b00 : a00, m01 = uB ? b01 : a01;
                v2f m10 = uB ? b10 : a10, m11 = uB ? b11 : a11;
                int r1 = r | (1 << PT);
                v2f s0 = st[r], s1 = st[r1];
                st[r]  = pk_cmac(pk_cmul(m00, s0), m01, s1);
                st[r1] = pk_cmac(pk_cmul(m10, s0), m11, s1);
            }
        } else {
            int cbit = (tid >> (PC - 3)) & 1;
            v2f m00 = cbit ? b00 : a00, m01 = cbit ? b01 : a01;
            v2f m10 = cbit ? b10 : a10, m11 = cbit ? b11 : a11;
            #pragma unroll
            for (int r = 0; r < NREG; ++r) {
                if ((r >> PT) & 1) continue;
                int r1 = r | (1 << PT);
                v2f s0 = st[r], s1 = st[r1];
                st[r]  = pk_cmac(pk_cmul(m00, s0), m01, s1);
                st[r1] = pk_cmac(pk_cmul(m10, s0), m11, s1);
            }
        }
    } else {
        constexpr int LM = 1 << (PT - 3);
        int tbit = (tid >> (PT - 3)) & 1;
        v2f dA = tbit ? a11 : a00, oA = tbit ? a10 : a01;
        v2f dB = tbit ? b11 : b00, oB = tbit ? b10 : b01;
        if constexpr (PC < 3) {
            #pragma unroll
            for (int r = 0; r < NREG; ++r) {
                const bool uB = (r >> PC) & 1;               // compile-time
                v2f d = uB ? dB : dA, o = uB ? oB : oA;
                v2f p = lxor2<LM>(st[r]);
                st[r] = pk_cmac(pk_cmul(d, st[r]), o, p);
            }
        } else {
            int cbit = (tid >> (PC - 3)) & 1;
            v2f d = cbit ? dB : dA, o = cbit ? oB : oA;
            #pragma unroll
            for (int r = 0; r < NREG; ++r) {
                v2f p = lxor2<LM>(st[r]);
                st[r] = pk_cmac(pk_cmul(d, st[r]), o, p);
            }
        }
    }
}

// CRX(ctrl at PC, tgt at PT<5)
template<int PC, int PT>
__device__ __forceinline__ void applyCRX(v2f* st, int tid, const float* cs) {
    v2f cs2 = M2(cs, 0);                 // (cos, sin)
    if constexpr (PT < 3) {
        if constexpr (PC < 3) {
            #pragma unroll
            for (int r = 0; r < NREG; ++r) {
                if (!((r >> PC) & 1) || ((r >> PT) & 1)) continue;
                int r1 = r | (1 << PT);
                v2f s0 = st[r], s1 = st[r1];
                st[r]  = pk_crx(cs2, s0, s1);
                st[r1] = pk_crx(cs2, s1, s0);
            }
        } else {
            int apply = (tid >> (PC - 3)) & 1;
            v2f id = { 1.f, 0.f };
            v2f cse = apply ? cs2 : id;
            #pragma unroll
            for (int r = 0; r < NREG; ++r) {
                if ((r >> PT) & 1) continue;
                int r1 = r | (1 << PT);
                v2f s0 = st[r], s1 = st[r1];
                st[r]  = pk_crx(cse, s0, s1);
                st[r1] = pk_crx(cse, s1, s0);
            }
        }
    } else {
        constexpr int LM = 1 << (PT - 3);
        if constexpr (PC < 3) {
            #pragma unroll
            for (int r = 0; r < NREG; ++r) {
                if (!((r >> PC) & 1)) continue;
                v2f p = lxor2<LM>(st[r]);
                st[r] = pk_crx(cs2, st[r], p);
            }
        } else {
            int apply = (tid >> (PC - 3)) & 1;
            v2f id = { 1.f, 0.f };
            v2f cse = apply ? cs2 : id;
            #pragma unroll
            for (int r = 0; r < NREG; ++r) {
                v2f p = lxor2<LM>(st[r]);
                st[r] = pk_crx(cse, st[r], p);
            }
        }
    }
}

__global__ __launch_bounds__(BLOCK)
void qfe_kernel(const float* __restrict__ params,
                const float* __restrict__ inputs,
                float* __restrict__ out) {
    const int b    = blockIdx.x;
    const int tid  = threadIdx.x;
    const int lane = tid & 63;
    const int w    = tid >> 6;

    __shared__ v2f buf[NREG * BLOCK];                       // 32 KB remap buffer
    __shared__ __align__(16) float mA[4 * 12 * 8];          // U = Rz*Ry*Rx (*RYembed l=0)
    __shared__ __align__(16) float mB[4 * 11 * 8];          // B = RX(ring1_j)*U(j+1)
    __shared__ __align__(16) float mcrx[4 * 24 * 2];        // (cos,sin)
    __shared__ float  redbuf[8][36];

    if (tid < 48) {
        int l = tid / 12, q = tid % 12;
        const float* pp = params + b * NPARAM + l * 60 + q * 3;
        float ax = pp[0]*0.5f, ay = pp[1]*0.5f, az = pp[2]*0.5f;
        float cx = cosf(ax), sx = sinf(ax);
        float cy = cosf(ay), sy = sinf(ay);
        float cz = cosf(az), sz = sinf(az);
        float2 a00 = make_float2( cy*cx,  sy*sx);
        float2 a01 = make_float2(-sy*cx, -cy*sx);
        float2 a10 = make_float2( sy*cx, -cy*sx);
        float2 a11 = make_float2( cy*cx, -sy*sx);
        float2 e0 = make_float2(cz, -sz);
        float2 e1 = make_float2(cz,  sz);
        float2 u00 = cmulf(e0, a00), u01 = cmulf(e0, a01);
        float2 u10 = cmulf(e1, a10), u11 = cmulf(e1, a11);
        if (l == 0) {   // fold RY input embedding
            float e = inputs[b * NQ + q] * 0.5f;
            float ce = cosf(e), se = sinf(e);
            float2 v00 = make_float2(u00.x*ce + u01.x*se, u00.y*ce + u01.y*se);
            float2 v01 = make_float2(-u00.x*se + u01.x*ce, -u00.y*se + u01.y*ce);
            float2 v10 = make_float2(u10.x*ce + u11.x*se, u10.y*ce + u11.y*se);
            float2 v11 = make_float2(-u10.x*se + u11.x*ce, -u10.y*se + u11.y*ce);
            u00 = v00; u01 = v01; u10 = v10; u11 = v11;
        }
        float* m = &mA[(l * 12 + q) * 8];
        m[0]=u00.x; m[1]=u00.y; m[2]=u01.x; m[3]=u01.y;
        m[4]=u10.x; m[5]=u10.y; m[6]=u11.x; m[7]=u11.y;
    }
    if (tid < 96) {
        int l = tid / 24, k = tid % 24;
        float a = params[b * NPARAM + l * 60 + 36 + k] * 0.5f;
        mcrx[(l * 24 + k) * 2]     = cosf(a);
        mcrx[(l * 24 + k) * 2 + 1] = sinf(a);
    }
    __syncthreads();
    if (tid < 44) {       // B(l,j) = RX(theta_ring1_j) * U(l, j+1)
        int l = tid / 11, j = tid % 11;
        const float* U = mA + (l * 12 + (j + 1)) * 8;
        float c = mcrx[(l * 24 + j) * 2], s = mcrx[(l * 24 + j) * 2 + 1];
        float* Bm = mB + (l * 11 + j) * 8;
        Bm[0] =  c*U[0] + s*U[5];
        Bm[1] =  c*U[1] - s*U[4];
        Bm[2] =  c*U[2] + s*U[7];
        Bm[3] =  c*U[3] - s*U[6];
        Bm[4] =  s*U[1] + c*U[4];
        Bm[5] = -s*U[0] + c*U[5];
        Bm[6] =  s*U[3] + c*U[6];
        Bm[7] = -s*U[2] + c*U[7];
    }
    __syncthreads();

    v2f st[NREG];
    #pragma unroll
    for (int r = 0; r < NREG; ++r) st[r] = (v2f){0.f, 0.f};
    if (tid == 0) st[0] = (v2f){1.f, 0.f};

    const int wtid = tid ^ ((tid & 0x30) >> 2);
    const int rb1 = rbase<0,1>(tid); const int sb1 = rb1 ^ ((rb1 & 0x30) >> 2);
    const int rb2 = rbase<1,2>(tid); const int sb2 = rb2 ^ ((rb2 & 0x30) >> 2);
    const int rb3 = rbase<2,3>(tid); const int sb3 = rb3 ^ ((rb3 & 0x30) >> 2);
    const int rb4 = rbase<3,4>(tid); const int sb4 = rb4 ^ ((rb4 & 0x30) >> 2);
    const int rb0 = rbase<4,0>(tid); const int sb0 = rb0 ^ ((rb0 & 0x30) >> 2);

    #pragma unroll 1
    for (int l = 0; l < 4; ++l) {
        const float* ma = mA + l * 96;
        const float* mb = mB + l * 88;
        const float* cl = mcrx + l * 48;
        // --- M0: q0@0,q1@1,q2@2,q3@3,q4@4 ---
        apply1q<0>(st, tid, ma + 0 * 8);
        fgate<0, 1>(st, tid, ma + 1 * 8, mb + 0 * 8);
        fgate<1, 2>(st, tid, ma + 2 * 8, mb + 1 * 8);
        fgate<2, 3>(st, tid, ma + 3 * 8, mb + 2 * 8);
        fgate<3, 4>(st, tid, ma + 4 * 8, mb + 3 * 8);
        remap<0, 1>(st, wtid, buf, sb1);
        // --- M1: q5@0,q6@1,q7@2,q8@3,q9@4; q4@6 ---
        fgate<6, 0>(st, tid, ma + 5 * 8, mb + 4 * 8);
        fgate<0, 1>(st, tid, ma + 6 * 8, mb + 5 * 8);
        fgate<1, 2>(st, tid, ma + 7 * 8, mb + 6 * 8);
        fgate<2, 3>(st, tid, ma + 8 * 8, mb + 7 * 8);
        fgate<3, 4>(st, tid, ma + 9 * 8, mb + 8 * 8);
        remap<1, 2>(st, wtid, buf, sb2);
        // --- M2: q10@0,q11@1,q0@2,q9@3,q8@4 ---
        fgate<3, 0>(st, tid, ma + 10 * 8, mb + 9 * 8);
        fgate<0, 1>(st, tid, ma + 11 * 8, mb + 10 * 8);
        applyCRX<1, 2>(st, tid, cl + 11 * 2);
        applyCRX<1, 0>(st, tid, cl + 12 * 2);
        applyCRX<0, 3>(st, tid, cl + 13 * 2);
        applyCRX<3, 4>(st, tid, cl + 14 * 2);
        remap<2, 3>(st, wtid, buf, sb3);
        // --- M3: q7@0,q6@1,q5@2,q4@3,q3@4; q8@6 ---
        applyCRX<6, 0>(st, tid, cl + 15 * 2);
        applyCRX<0, 1>(st, tid, cl + 16 * 2);
        applyCRX<1, 2>(st, tid, cl + 17 * 2);
        applyCRX<2, 3>(st, tid, cl + 18 * 2);
        applyCRX<3, 4>(st, tid, cl + 19 * 2);
        remap<3, 4>(st, wtid, buf, sb4);
        // --- M4: q2@0,q1@1,q0@2,q11@3; q3@5 ---
        applyCRX<5, 0>(st, tid, cl + 20 * 2);
        applyCRX<0, 1>(st, tid, cl + 21 * 2);
        applyCRX<1, 2>(st, tid, cl + 22 * 2);
        applyCRX<2, 3>(st, tid, cl + 23 * 2);
        remap<4, 0>(st, wtid, buf, sb0);
    }

    // ---- epilogue: expectations under M0 ----
    float nn[NREG];
    #pragma unroll
    for (int r = 0; r < NREG; ++r) nn[r] = st[r].x*st[r].x + st[r].y*st[r].y;
    float T  = ((nn[0]+nn[1])+(nn[2]+nn[3])) + ((nn[4]+nn[5])+(nn[6]+nn[7]));
    float Z0 = ((nn[0]-nn[1])+(nn[2]-nn[3])) + ((nn[4]-nn[5])+(nn[6]-nn[7]));
    float Z1 = ((nn[0]+nn[1])-(nn[2]+nn[3])) + ((nn[4]+nn[5])-(nn[6]+nn[7]));
    float Z2 = ((nn[0]+nn[1])+(nn[2]+nn[3])) - ((nn[4]+nn[5])+(nn[6]+nn[7]));

    __syncthreads();                       // WAR vs last remap reads
    #pragma unroll
    for (int r = 0; r < NREG; ++r) buf[r * BLOCK + tid] = st[r];   // plain layout
    __syncthreads();

#define EXP_REG(q, B, ZV) { \
    v2f acc = {0.f, 0.f}; \
    _Pragma("unroll") \
    for (int r = 0; r < NREG; ++r) { \
        if ((r >> (B)) & 1) continue; \
        acc = pk_cjmac(acc, st[r], st[r | (1 << (B))]); \
    } \
    float X = wsum(2.f*acc.x), Y = wsum(2.f*acc.y), Z = wsum(ZV); \
    if (lane == 63) { redbuf[w][(q)] = X; redbuf[w][12+(q)] = Y; redbuf[w][24+(q)] = Z; } }

#define EXP_DPP(q, LM, TB) { \
    v2f acc = {0.f, 0.f}; \
    _Pragma("unroll") \
    for (int r = 0; r < NREG; ++r) { \
        v2f p = lxor2<LM>(st[r]); \
        acc = pk_cjmac(acc, st[r], p); \
    } \
    float zs = ((tid >> (TB)) & 1) ? -1.f : 1.f; \
    float X = wsum(acc.x), Y = wsum(zs*acc.y), Z = wsum(zs*T); \
    if (lane == 63) { redbuf[w][(q)] = X; redbuf[w][12+(q)] = Y; redbuf[w][24+(q)] = Z; } }

#define EXP_BUF(q, XM, TB) { \
    v2f acc = {0.f, 0.f}; \
    int pt = tid ^ (XM); \
    _Pragma("unroll") \
    for (int r = 0; r < NREG; ++r) { \
        acc = pk_cjmac(acc, st[r], buf[r * BLOCK + pt]); \
    } \
    float zs = ((tid >> (TB)) & 1) ? -1.f : 1.f; \
    float X = wsum(acc.x), Y = wsum(zs*acc.y), Z = wsum(zs*T); \
    if (lane == 63) { redbuf[w][(q)] = X; redbuf[w][12+(q)] = Y; redbuf[w][24+(q)] = Z; } }

    EXP_REG(0, 0, Z0)  EXP_REG(1, 1, Z1)  EXP_REG(2, 2, Z2)
    EXP_DPP(3, 1, 0)   EXP_DPP(4, 2, 1)
    EXP_BUF(10, 4, 2)  EXP_BUF(11, 8, 3)  EXP_BUF(9, 16, 4)  EXP_BUF(8, 32, 5)
    EXP_BUF(5, 64, 6)  EXP_BUF(6, 128, 7) EXP_BUF(7, 256, 8)

    __syncthreads();
    if (tid < 36) {
        float acc = 0.f;
        #pragma unroll
        for (int i = 0; i < 8; ++i) acc += redbuf[i][tid];
        out[b * 36 + tid] = acc;
    }
}

extern "C" void kernel_launch(void* const* d_in, const int* in_sizes, int n_in,
                              void* d_out, int out_size, void* d_ws, size_t ws_size,
                              hipStream_t stream) {
    const float* params = (const float*)d_in[0];   // (1024, 240) float32
    const float* inputs = (const float*)d_in[1];   // (1024, 12)  float32
    float* out = (float*)d_out;                    // (1024, 36)  float32
    qfe_kernel<<<1024, BLOCK, 0, stream>>>(params, inputs, out);
}

// Round 12
// 110.120 us; speedup vs baseline: 2.1180x; 1.1296x over previous
//
#include <hip/hip_runtime.h>
#include <hip/hip_fp16.h>

#define NQ     12
#define NPARAM 240       // 12*4*5
#define BLOCK  512
#define NREG   8

typedef float v2f __attribute__((ext_vector_type(2)));
typedef unsigned int h2;     // packed f16 complex: lo=re, hi=im
#define IDH 0x00003C00u      // (1.0, 0.0) in packed f16

// ---- packed f16 complex primitives (v_pk_*_f16, full rate = 2x f32 flops) ----
__device__ __forceinline__ h2 pk_cmul16(h2 a, h2 b) {
    h2 t;
    asm("v_pk_mul_f16 %0, %1, %2 op_sel:[0,0] op_sel_hi:[0,1]\n\t"
        "v_pk_fma_f16 %0, %1, %2, %0 op_sel:[1,1,0] op_sel_hi:[1,0,1] neg_lo:[1,0,0]"
        : "=&v"(t) : "v"(a), "v"(b));
    return t;
}
__device__ __forceinline__ h2 pk_cmac16(h2 t0, h2 a, h2 b) {
    h2 t;
    asm("v_pk_fma_f16 %0, %2, %3, %1 op_sel:[0,0,0] op_sel_hi:[0,1,1]\n\t"
        "v_pk_fma_f16 %0, %2, %3, %0 op_sel:[1,1,0] op_sel_hi:[1,0,1] neg_lo:[1,0,0]"
        : "=&v"(t) : "v"(t0), "v"(a), "v"(b));
    return t;
}
// CRX halfstep: cs2=(c,s): lo = c*sx + s*py ; hi = c*sy - s*px
__device__ __forceinline__ h2 pk_crx16(h2 cs2, h2 s, h2 p) {
    h2 t;
    asm("v_pk_mul_f16 %0, %1, %2 op_sel:[0,0] op_sel_hi:[0,1]\n\t"
        "v_pk_fma_f16 %0, %1, %3, %0 op_sel:[1,1,0] op_sel_hi:[1,0,1] neg_hi:[0,1,0]"
        : "=&v"(t) : "v"(cs2), "v"(s), "v"(p));
    return t;
}
// f32 conj-accumulate for epilogue: acc += conj(s)(.)p
__device__ __forceinline__ v2f pk_cjmac(v2f a0, v2f s, v2f p) {
    v2f t;
    asm("v_pk_fma_f32 %0, %2, %3, %1 op_sel:[0,0,0] op_sel_hi:[0,1,1]\n\t"
        "v_pk_fma_f32 %0, %2, %3, %0 op_sel:[1,1,0] op_sel_hi:[1,0,1] neg_hi:[1,0,0]"
        : "=&v"(t) : "v"(a0), "v"(s), "v"(p));
    return t;
}

__device__ __forceinline__ h2 packh2(float x, float y) {
    return ((h2)__half_as_ushort(__float2half_rn(y)) << 16) |
           (h2)__half_as_ushort(__float2half_rn(x));
}
__device__ __forceinline__ v2f uph2(h2 u) {
    return (v2f){ __half2float(__ushort_as_half((unsigned short)(u & 0xffff))),
                  __half2float(__ushort_as_half((unsigned short)(u >> 16))) };
}

// Storage position p for a qubit (unchanged from R10/R11):
//   p in [0,3)  -> register bit p of r       : pure VALU
//   p in [3,5)  -> lane bit (p-3), DPP       : pure VALU
//   p in [5,9)  -> lane bit (p-3)            : LDS pipe (avoid for gates)
//   p in [9,12) -> tid bit (p-3) = wave bit  : select-only for ctrl
// f16/b32 remap bank note: with 4B elements banks = e[4:0] over 32-lane
// groups; all five transitions give >=4 varying bank bits -> worst 2-way,
// which is free (m136). Swizzle dropped.

constexpr int QMAP[5][12] = {
    // pos:   0   1   2   3   4    5   6   7   8    9  10  11
    /*M0*/ {  0,  1,  2,  3,  4,  10, 11,  9,  8,   5,  6,  7},
    /*M1*/ {  5,  6,  7,  8,  9,   3,  4, 10, 11,   0,  1,  2},
    /*M2*/ { 10, 11,  0,  9,  8,   3,  4,  5,  6,   1,  2,  7},
    /*M3*/ {  7,  6,  5,  4,  3,   9,  8, 10, 11,   0,  1,  2},
    /*M4*/ {  2,  1,  0, 11,  4,   3,  9,  8, 10,   5,  6,  7},
};

constexpr int posof(int m, int q) {
    for (int p = 0; p < 12; ++p) if (QMAP[m][p] == q) return p;
    return -1;
}
constexpr int ebit(int p) { return p < 3 ? 9 + p : p - 3; }
constexpr int roff(int MA, int MB, int r) {
    int off = 0;
    for (int p = 0; p < 3; ++p)
        off |= ((r >> p) & 1) << ebit(posof(MA, QMAP[MB][p]));
    return off;
}

template<int MA, int MB>
__device__ __forceinline__ int rbase(int tid) {
    int base = 0;
    #pragma unroll
    for (int p = 3; p < 12; ++p)
        base |= ((tid >> (p - 3)) & 1) << ebit(posof(MA, QMAP[MB][p]));
    return base;
}

template<int MA, int MB>
__device__ __forceinline__ void remap(h2* st, int tid, h2* bufh, int base) {
    __syncthreads();                       // WAR vs prior buf readers
    #pragma unroll
    for (int r = 0; r < NREG; ++r) bufh[r * BLOCK + tid] = st[r];
    __syncthreads();
    #pragma unroll
    for (int r = 0; r < NREG; ++r) st[r] = bufh[base ^ roff(MA, MB, r)];
}

template<int LM>
__device__ __forceinline__ int lxori(int v) {
    if constexpr (LM == 1) {        // quad_perm [1,0,3,2] = xor 1, VALU pipe
        return __builtin_amdgcn_update_dpp(v, v, 0xB1, 0xF, 0xF, false);
    } else if constexpr (LM == 2) { // quad_perm [2,3,0,1] = xor 2, VALU pipe
        return __builtin_amdgcn_update_dpp(v, v, 0x4E, 0xF, 0xF, false);
    } else {
        return __shfl_xor(v, LM, 64);
    }
}
template<int LM>
__device__ __forceinline__ h2 lxor_h(h2 v) { return (h2)lxori<LM>((int)v); }
template<int LM>
__device__ __forceinline__ v2f lxor2(v2f v) {
    v2f p = { __int_as_float(lxori<LM>(__float_as_int(v.x))),
              __int_as_float(lxori<LM>(__float_as_int(v.y))) };
    return p;
}

// DPP wave-64 sum; total lands in lane 63
__device__ __forceinline__ float wsum(float x) {
    x += __int_as_float(__builtin_amdgcn_update_dpp(0, __float_as_int(x), 0x111, 0xF, 0xF, true));
    x += __int_as_float(__builtin_amdgcn_update_dpp(0, __float_as_int(x), 0x112, 0xF, 0xF, true));
    x += __int_as_float(__builtin_amdgcn_update_dpp(0, __float_as_int(x), 0x114, 0xF, 0xF, true));
    x += __int_as_float(__builtin_amdgcn_update_dpp(0, __float_as_int(x), 0x118, 0xF, 0xF, true));
    x += __int_as_float(__builtin_amdgcn_update_dpp(0, __float_as_int(x), 0x142, 0xa, 0xF, false));
    x += __int_as_float(__builtin_amdgcn_update_dpp(0, __float_as_int(x), 0x143, 0xc, 0xF, false));
    return x;
}

__device__ __forceinline__ float2 cmulf(float2 a, float2 b) {
    return make_float2(a.x*b.x - a.y*b.y, a.x*b.y + a.y*b.x);
}

// plain 1q gate at position P (only U(q0) at pos 0 uses this)
template<int P>
__device__ __forceinline__ void apply1q(h2* st, int tid, const h2* m) {
    h2 u00 = m[0], u01 = m[1], u10 = m[2], u11 = m[3];
    if constexpr (P < 3) {
        #pragma unroll
        for (int r = 0; r < NREG; ++r) {
            if ((r >> P) & 1) continue;
            int r1 = r | (1 << P);
            h2 s0 = st[r], s1 = st[r1];
            st[r]  = pk_cmac16(pk_cmul16(u00, s0), u01, s1);
            st[r1] = pk_cmac16(pk_cmul16(u10, s0), u11, s1);
        }
    } else {
        constexpr int LM = 1 << (P - 3);
        int bit = (tid >> (P - 3)) & 1;
        h2 d = bit ? u11 : u00;
        h2 o = bit ? u10 : u01;
        #pragma unroll
        for (int r = 0; r < NREG; ++r) {
            h2 p = lxor_h<LM>(st[r]);
            st[r] = pk_cmac16(pk_cmul16(d, st[r]), o, p);
        }
    }
}

// fused ring1 gate: A (ctrl=0) / B = RX*A (ctrl=1); PT < 5 by schedule
template<int PC, int PT>
__device__ __forceinline__ void fgate(h2* st, int tid, const h2* A, const h2* B) {
    h2 a00 = A[0], a01 = A[1], a10 = A[2], a11 = A[3];
    h2 b00 = B[0], b01 = B[1], b10 = B[2], b11 = B[3];
    if constexpr (PT < 3) {
        if constexpr (PC < 3) {
            #pragma unroll
            for (int r = 0; r < NREG; ++r) {
                if ((r >> PT) & 1) continue;
                const bool uB = (r >> PC) & 1;               // compile-time
                h2 m00 = uB ? b00 : a00, m01 = uB ? b01 : a01;
                h2 m10 = uB ? b10 : a10, m11 = uB ? b11 : a11;
                int r1 = r | (1 << PT);
                h2 s0 = st[r], s1 = st[r1];
                st[r]  = pk_cmac16(pk_cmul16(m00, s0), m01, s1);
                st[r1] = pk_cmac16(pk_cmul16(m10, s0), m11, s1);
            }
        } else {
            int cbit = (tid >> (PC - 3)) & 1;
            h2 m00 = cbit ? b00 : a00, m01 = cbit ? b01 : a01;
            h2 m10 = cbit ? b10 : a10, m11 = cbit ? b11 : a11;
            #pragma unroll
            for (int r = 0; r < NREG; ++r) {
                if ((r >> PT) & 1) continue;
                int r1 = r | (1 << PT);
                h2 s0 = st[r], s1 = st[r1];
                st[r]  = pk_cmac16(pk_cmul16(m00, s0), m01, s1);
                st[r1] = pk_cmac16(pk_cmul16(m10, s0), m11, s1);
            }
        }
    } else {
        constexpr int LM = 1 << (PT - 3);
        int tbit = (tid >> (PT - 3)) & 1;
        h2 dA = tbit ? a11 : a00, oA = tbit ? a10 : a01;
        h2 dB = tbit ? b11 : b00, oB = tbit ? b10 : b01;
        if constexpr (PC < 3) {
            #pragma unroll
            for (int r = 0; r < NREG; ++r) {
                const bool uB = (r >> PC) & 1;               // compile-time
                h2 d = uB ? dB : dA, o = uB ? oB : oA;
                h2 p = lxor_h<LM>(st[r]);
                st[r] = pk_cmac16(pk_cmul16(d, st[r]), o, p);
            }
        } else {
            int cbit = (tid >> (PC - 3)) & 1;
            h2 d = cbit ? dB : dA, o = cbit ? oB : oA;
            #pragma unroll
            for (int r = 0; r < NREG; ++r) {
                h2 p = lxor_h<LM>(st[r]);
                st[r] = pk_cmac16(pk_cmul16(d, st[r]), o, p);
            }
        }
    }
}

// CRX(ctrl at PC, tgt at PT<5)
template<int PC, int PT>
__device__ __forceinline__ void applyCRX(h2* st, int tid, const h2* cs) {
    h2 cs2 = cs[0];                      // packed (cos, sin)
    if constexpr (PT < 3) {
        if constexpr (PC < 3) {
            #pragma unroll
            for (int r = 0; r < NREG; ++r) {
                if (!((r >> PC) & 1) || ((r >> PT) & 1)) continue;
                int r1 = r | (1 << PT);
                h2 s0 = st[r], s1 = st[r1];
                st[r]  = pk_crx16(cs2, s0, s1);
                st[r1] = pk_crx16(cs2, s1, s0);
            }
        } else {
            int apply = (tid >> (PC - 3)) & 1;
            h2 cse = apply ? cs2 : IDH;
            #pragma unroll
            for (int r = 0; r < NREG; ++r) {
                if ((r >> PT) & 1) continue;
                int r1 = r | (1 << PT);
                h2 s0 = st[r], s1 = st[r1];
                st[r]  = pk_crx16(cse, s0, s1);
                st[r1] = pk_crx16(cse, s1, s0);
            }
        }
    } else {
        constexpr int LM = 1 << (PT - 3);
        if constexpr (PC < 3) {
            #pragma unroll
            for (int r = 0; r < NREG; ++r) {
                if (!((r >> PC) & 1)) continue;
                h2 p = lxor_h<LM>(st[r]);
                st[r] = pk_crx16(cs2, st[r], p);
            }
        } else {
            int apply = (tid >> (PC - 3)) & 1;
            h2 cse = apply ? cs2 : IDH;
            #pragma unroll
            for (int r = 0; r < NREG; ++r) {
                h2 p = lxor_h<LM>(st[r]);
                st[r] = pk_crx16(cse, st[r], p);
            }
        }
    }
}

__global__ __launch_bounds__(BLOCK)
void qfe_kernel(const float* __restrict__ params,
                const float* __restrict__ inputs,
                float* __restrict__ out) {
    const int b    = blockIdx.x;
    const int tid  = threadIdx.x;
    const int lane = tid & 63;
    const int w    = tid >> 6;

    __shared__ v2f buf[NREG * BLOCK];      // 32 KB: f16 remaps (16 KB) + f32 epilogue
    h2* bufh = (h2*)buf;
    __shared__ __align__(16) h2 mA[4 * 12 * 4];   // packed f16 matrices
    __shared__ __align__(16) h2 mB[4 * 11 * 4];
    __shared__ __align__(16) h2 mcrx[4 * 24];     // packed (cos,sin)
    __shared__ float  redbuf[8][36];

    if (tid < 48) {
        int l = tid / 12, q = tid % 12;
        const float* pp = params + b * NPARAM + l * 60 + q * 3;
        float ax = pp[0]*0.5f, ay = pp[1]*0.5f, az = pp[2]*0.5f;
        float cx = cosf(ax), sx = sinf(ax);
        float cy = cosf(ay), sy = sinf(ay);
        float cz = cosf(az), sz = sinf(az);
        float2 a00 = make_float2( cy*cx,  sy*sx);
        float2 a01 = make_float2(-sy*cx, -cy*sx);
        float2 a10 = make_float2( sy*cx, -cy*sx);
        float2 a11 = make_float2( cy*cx, -sy*sx);
        float2 e0 = make_float2(cz, -sz);
        float2 e1 = make_float2(cz,  sz);
        float2 u00 = cmulf(e0, a00), u01 = cmulf(e0, a01);
        float2 u10 = cmulf(e1, a10), u11 = cmulf(e1, a11);
        if (l == 0) {   // fold RY input embedding
            float e = inputs[b * NQ + q] * 0.5f;
            float ce = cosf(e), se = sinf(e);
            float2 v00 = make_float2(u00.x*ce + u01.x*se, u00.y*ce + u01.y*se);
            float2 v01 = make_float2(-u00.x*se + u01.x*ce, -u00.y*se + u01.y*ce);
            float2 v10 = make_float2(u10.x*ce + u11.x*se, u10.y*ce + u11.y*se);
            float2 v11 = make_float2(-u10.x*se + u11.x*ce, -u10.y*se + u11.y*ce);
            u00 = v00; u01 = v01; u10 = v10; u11 = v11;
        }
        h2* m = &mA[(l * 12 + q) * 4];
        m[0] = packh2(u00.x, u00.y); m[1] = packh2(u01.x, u01.y);
        m[2] = packh2(u10.x, u10.y); m[3] = packh2(u11.x, u11.y);
    }
    if (tid < 96) {
        int l = tid / 24, k = tid % 24;
        float a = params[b * NPARAM + l * 60 + 36 + k] * 0.5f;
        mcrx[l * 24 + k] = packh2(cosf(a), sinf(a));
    }
    __syncthreads();
    if (tid < 44) {       // B(l,j) = RX(theta_ring1_j) * U(l, j+1)
        int l = tid / 11, j = tid % 11;
        const h2* U = &mA[(l * 12 + (j + 1)) * 4];
        v2f u00 = uph2(U[0]), u01 = uph2(U[1]), u10 = uph2(U[2]), u11 = uph2(U[3]);
        v2f csv = uph2(mcrx[l * 24 + j]);
        float c = csv.x, s = csv.y;
        h2* Bm = &mB[(l * 11 + j) * 4];
        Bm[0] = packh2( c*u00.x + s*u10.y,  c*u00.y - s*u10.x);
        Bm[1] = packh2( c*u01.x + s*u11.y,  c*u01.y - s*u11.x);
        Bm[2] = packh2( s*u00.y + c*u10.x, -s*u00.x + c*u10.y);
        Bm[3] = packh2( s*u01.y + c*u11.x, -s*u01.x + c*u11.y);
    }
    __syncthreads();

    h2 st[NREG];
    #pragma unroll
    for (int r = 0; r < NREG; ++r) st[r] = 0u;
    if (tid == 0) st[0] = IDH;

    const int rb1 = rbase<0,1>(tid);
    const int rb2 = rbase<1,2>(tid);
    const int rb3 = rbase<2,3>(tid);
    const int rb4 = rbase<3,4>(tid);
    const int rb0 = rbase<4,0>(tid);

    #pragma unroll 1
    for (int l = 0; l < 4; ++l) {
        const h2* ma = mA + l * 48;
        const h2* mb = mB + l * 44;
        const h2* cl = mcrx + l * 24;
        // --- M0: q0@0,q1@1,q2@2,q3@3,q4@4 ---
        apply1q<0>(st, tid, ma + 0 * 4);
        fgate<0, 1>(st, tid, ma + 1 * 4, mb + 0 * 4);
        fgate<1, 2>(st, tid, ma + 2 * 4, mb + 1 * 4);
        fgate<2, 3>(st, tid, ma + 3 * 4, mb + 2 * 4);
        fgate<3, 4>(st, tid, ma + 4 * 4, mb + 3 * 4);
        remap<0, 1>(st, tid, bufh, rb1);
        // --- M1: q5@0,q6@1,q7@2,q8@3,q9@4; q4@6 ---
        fgate<6, 0>(st, tid, ma + 5 * 4, mb + 4 * 4);
        fgate<0, 1>(st, tid, ma + 6 * 4, mb + 5 * 4);
        fgate<1, 2>(st, tid, ma + 7 * 4, mb + 6 * 4);
        fgate<2, 3>(st, tid, ma + 8 * 4, mb + 7 * 4);
        fgate<3, 4>(st, tid, ma + 9 * 4, mb + 8 * 4);
        remap<1, 2>(st, tid, bufh, rb2);
        // --- M2: q10@0,q11@1,q0@2,q9@3,q8@4 ---
        fgate<3, 0>(st, tid, ma + 10 * 4, mb + 9 * 4);
        fgate<0, 1>(st, tid, ma + 11 * 4, mb + 10 * 4);
        applyCRX<1, 2>(st, tid, cl + 11);
        applyCRX<1, 0>(st, tid, cl + 12);
        applyCRX<0, 3>(st, tid, cl + 13);
        applyCRX<3, 4>(st, tid, cl + 14);
        remap<2, 3>(st, tid, bufh, rb3);
        // --- M3: q7@0,q6@1,q5@2,q4@3,q3@4; q8@6 ---
        applyCRX<6, 0>(st, tid, cl + 15);
        applyCRX<0, 1>(st, tid, cl + 16);
        applyCRX<1, 2>(st, tid, cl + 17);
        applyCRX<2, 3>(st, tid, cl + 18);
        applyCRX<3, 4>(st, tid, cl + 19);
        remap<3, 4>(st, tid, bufh, rb4);
        // --- M4: q2@0,q1@1,q0@2,q11@3; q3@5 ---
        applyCRX<5, 0>(st, tid, cl + 20);
        applyCRX<0, 1>(st, tid, cl + 21);
        applyCRX<1, 2>(st, tid, cl + 22);
        applyCRX<2, 3>(st, tid, cl + 23);
        remap<4, 0>(st, tid, bufh, rb0);
    }

    // ---- epilogue (f32): convert once, reuse R11-validated reduction ----
    v2f stf[NREG];
    #pragma unroll
    for (int r = 0; r < NREG; ++r) stf[r] = uph2(st[r]);

    float nn[NREG];
    #pragma unroll
    for (int r = 0; r < NREG; ++r) nn[r] = stf[r].x*stf[r].x + stf[r].y*stf[r].y;
    float T  = ((nn[0]+nn[1])+(nn[2]+nn[3])) + ((nn[4]+nn[5])+(nn[6]+nn[7]));
    float Z0 = ((nn[0]-nn[1])+(nn[2]-nn[3])) + ((nn[4]-nn[5])+(nn[6]-nn[7]));
    float Z1 = ((nn[0]+nn[1])-(nn[2]+nn[3])) + ((nn[4]+nn[5])-(nn[6]+nn[7]));
    float Z2 = ((nn[0]+nn[1])+(nn[2]+nn[3])) - ((nn[4]+nn[5])+(nn[6]+nn[7]));

    __syncthreads();                       // WAR vs last remap reads
    #pragma unroll
    for (int r = 0; r < NREG; ++r) buf[r * BLOCK + tid] = stf[r];   // f32 layout
    __syncthreads();

#define EXP_REG(q, B, ZV) { \
    v2f acc = {0.f, 0.f}; \
    _Pragma("unroll") \
    for (int r = 0; r < NREG; ++r) { \
        if ((r >> (B)) & 1) continue; \
        acc = pk_cjmac(acc, stf[r], stf[r | (1 << (B))]); \
    } \
    float X = wsum(2.f*acc.x), Y = wsum(2.f*acc.y), Z = wsum(ZV); \
    if (lane == 63) { redbuf[w][(q)] = X; redbuf[w][12+(q)] = Y; redbuf[w][24+(q)] = Z; } }

#define EXP_DPP(q, LM, TB) { \
    v2f acc = {0.f, 0.f}; \
    _Pragma("unroll") \
    for (int r = 0; r < NREG; ++r) { \
        v2f p = lxor2<LM>(stf[r]); \
        acc = pk_cjmac(acc, stf[r], p); \
    } \
    float zs = ((tid >> (TB)) & 1) ? -1.f : 1.f; \
    float X = wsum(acc.x), Y = wsum(zs*acc.y), Z = wsum(zs*T); \
    if (lane == 63) { redbuf[w][(q)] = X; redbuf[w][12+(q)] = Y; redbuf[w][24+(q)] = Z; } }

#define EXP_BUF(q, XM, TB) { \
    v2f acc = {0.f, 0.f}; \
    int pt = tid ^ (XM); \
    _Pragma("unroll") \
    for (int r = 0; r < NREG; ++r) { \
        acc = pk_cjmac(acc, stf[r], buf[r * BLOCK + pt]); \
    } \
    float zs = ((tid >> (TB)) & 1) ? -1.f : 1.f; \
    float X = wsum(acc.x), Y = wsum(zs*acc.y), Z = wsum(zs*T); \
    if (lane == 63) { redbuf[w][(q)] = X; redbuf[w][12+(q)] = Y; redbuf[w][24+(q)] = Z; } }

    EXP_REG(0, 0, Z0)  EXP_REG(1, 1, Z1)  EXP_REG(2, 2, Z2)
    EXP_DPP(3, 1, 0)   EXP_DPP(4, 2, 1)
    EXP_BUF(10, 4, 2)  EXP_BUF(11, 8, 3)  EXP_BUF(9, 16, 4)  EXP_BUF(8, 32, 5)
    EXP_BUF(5, 64, 6)  EXP_BUF(6, 128, 7) EXP_BUF(7, 256, 8)

    __syncthreads();
    if (tid < 36) {
        float acc = 0.f;
        #pragma unroll
        for (int i = 0; i < 8; ++i) acc += redbuf[i][tid];
        out[b * 36 + tid] = acc;
    }
}

extern "C" void kernel_launch(void* const* d_in, const int* in_sizes, int n_in,
                              void* d_out, int out_size, void* d_ws, size_t ws_size,
                              hipStream_t stream) {
    const float* params = (const float*)d_in[0];   // (1024, 240) float32
    const float* inputs = (const float*)d_in[1];   // (1024, 12)  float32
    float* out = (float*)d_out;                    // (1024, 36)  float32
    qfe_kernel<<<1024, BLOCK, 0, stream>>>(params, inputs, out);
}

// Round 13
// 109.844 us; speedup vs baseline: 2.1234x; 1.0025x over previous
//
#include <hip/hip_runtime.h>
#include <hip/hip_fp16.h>

#define NQ     12
#define NPARAM 240       // 12*4*5
#define BLOCK  512
#define NREG   8

typedef float v2f __attribute__((ext_vector_type(2)));
typedef unsigned int h2;     // packed f16 complex: lo=re, hi=im
#define IDH 0x00003C00u      // (1.0, 0.0) in packed f16

// ---- packed f16 complex primitives (v_pk_*_f16, full rate = 2x f32 flops) ----
__device__ __forceinline__ h2 pk_cmul16(h2 a, h2 b) {
    h2 t;
    asm("v_pk_mul_f16 %0, %1, %2 op_sel:[0,0] op_sel_hi:[0,1]\n\t"
        "v_pk_fma_f16 %0, %1, %2, %0 op_sel:[1,1,0] op_sel_hi:[1,0,1] neg_lo:[1,0,0]"
        : "=&v"(t) : "v"(a), "v"(b));
    return t;
}
__device__ __forceinline__ h2 pk_cmac16(h2 t0, h2 a, h2 b) {
    h2 t;
    asm("v_pk_fma_f16 %0, %2, %3, %1 op_sel:[0,0,0] op_sel_hi:[0,1,1]\n\t"
        "v_pk_fma_f16 %0, %2, %3, %0 op_sel:[1,1,0] op_sel_hi:[1,0,1] neg_lo:[1,0,0]"
        : "=&v"(t) : "v"(t0), "v"(a), "v"(b));
    return t;
}
// CRX halfstep: cs2=(c,s): lo = c*sx + s*py ; hi = c*sy - s*px
__device__ __forceinline__ h2 pk_crx16(h2 cs2, h2 s, h2 p) {
    h2 t;
    asm("v_pk_mul_f16 %0, %1, %2 op_sel:[0,0] op_sel_hi:[0,1]\n\t"
        "v_pk_fma_f16 %0, %1, %3, %0 op_sel:[1,1,0] op_sel_hi:[1,0,1] neg_hi:[0,1,0]"
        : "=&v"(t) : "v"(cs2), "v"(s), "v"(p));
    return t;
}
// f32 conj-accumulate for epilogue: acc += conj(s)(.)p
__device__ __forceinline__ v2f pk_cjmac(v2f a0, v2f s, v2f p) {
    v2f t;
    asm("v_pk_fma_f32 %0, %2, %3, %1 op_sel:[0,0,0] op_sel_hi:[0,1,1]\n\t"
        "v_pk_fma_f32 %0, %2, %3, %0 op_sel:[1,1,0] op_sel_hi:[1,0,1] neg_hi:[1,0,0]"
        : "=&v"(t) : "v"(a0), "v"(s), "v"(p));
    return t;
}

__device__ __forceinline__ h2 packh2(float x, float y) {
    return ((h2)__half_as_ushort(__float2half_rn(y)) << 16) |
           (h2)__half_as_ushort(__float2half_rn(x));
}
__device__ __forceinline__ v2f uph2(h2 u) {
    return (v2f){ __half2float(__ushort_as_half((unsigned short)(u & 0xffff))),
                  __half2float(__ushort_as_half((unsigned short)(u >> 16))) };
}

// Storage position p for a qubit:
//   p in [0,3)  -> register bit p of r       : pure VALU
//   p in [3,5)  -> lane bit (p-3), DPP       : pure VALU
//   p in [5,9)  -> lane bit (p-3)            : shfl (bpermute) / buf partner
//   p in [9,12) -> tid bit (p-3) = wave bit  : select-only for ctrl
// R13: 4-map cycle M4 -> M1 -> M2 -> M3 -> M4 (16 remaps, was 20). The old
// M0 gate block runs directly under M4; only F(2,3) needs one shfl_xor(4)
// gate (8 bpermutes), cheaper than the eliminated remap (16 LDS ops + 2
// barriers). Init and epilogue are under M4. All four transitions' remap
// reads verified <=2-way on banks (free per m136).

constexpr int QMAP[5][12] = {
    // pos:   0   1   2   3   4    5   6   7   8    9  10  11
    /*M0*/ {  0,  1,  2,  3,  4,  10, 11,  9,  8,   5,  6,  7},   // unused (kept for indexing)
    /*M1*/ {  5,  6,  7,  8,  9,   3,  4, 10, 11,   0,  1,  2},
    /*M2*/ { 10, 11,  0,  9,  8,   3,  4,  5,  6,   1,  2,  7},
    /*M3*/ {  7,  6,  5,  4,  3,   9,  8, 10, 11,   0,  1,  2},
    /*M4*/ {  2,  1,  0, 11,  4,   3,  9,  8, 10,   5,  6,  7},
};

constexpr int posof(int m, int q) {
    for (int p = 0; p < 12; ++p) if (QMAP[m][p] == q) return p;
    return -1;
}
constexpr int ebit(int p) { return p < 3 ? 9 + p : p - 3; }
constexpr int roff(int MA, int MB, int r) {
    int off = 0;
    for (int p = 0; p < 3; ++p)
        off |= ((r >> p) & 1) << ebit(posof(MA, QMAP[MB][p]));
    return off;
}

template<int MA, int MB>
__device__ __forceinline__ int rbase(int tid) {
    int base = 0;
    #pragma unroll
    for (int p = 3; p < 12; ++p)
        base |= ((tid >> (p - 3)) & 1) << ebit(posof(MA, QMAP[MB][p]));
    return base;
}

template<int MA, int MB>
__device__ __forceinline__ void remap(h2* st, int tid, h2* bufh, int base) {
    __syncthreads();                       // WAR vs prior buf readers
    #pragma unroll
    for (int r = 0; r < NREG; ++r) bufh[r * BLOCK + tid] = st[r];
    __syncthreads();
    #pragma unroll
    for (int r = 0; r < NREG; ++r) st[r] = bufh[base ^ roff(MA, MB, r)];
}

template<int LM>
__device__ __forceinline__ int lxori(int v) {
    if constexpr (LM == 1) {        // quad_perm [1,0,3,2] = xor 1, VALU pipe
        return __builtin_amdgcn_update_dpp(v, v, 0xB1, 0xF, 0xF, false);
    } else if constexpr (LM == 2) { // quad_perm [2,3,0,1] = xor 2, VALU pipe
        return __builtin_amdgcn_update_dpp(v, v, 0x4E, 0xF, 0xF, false);
    } else {
        return __shfl_xor(v, LM, 64);
    }
}
template<int LM>
__device__ __forceinline__ h2 lxor_h(h2 v) { return (h2)lxori<LM>((int)v); }
template<int LM>
__device__ __forceinline__ v2f lxor2(v2f v) {
    v2f p = { __int_as_float(lxori<LM>(__float_as_int(v.x))),
              __int_as_float(lxori<LM>(__float_as_int(v.y))) };
    return p;
}

// DPP wave-64 sum; total lands in lane 63
__device__ __forceinline__ float wsum(float x) {
    x += __int_as_float(__builtin_amdgcn_update_dpp(0, __float_as_int(x), 0x111, 0xF, 0xF, true));
    x += __int_as_float(__builtin_amdgcn_update_dpp(0, __float_as_int(x), 0x112, 0xF, 0xF, true));
    x += __int_as_float(__builtin_amdgcn_update_dpp(0, __float_as_int(x), 0x114, 0xF, 0xF, true));
    x += __int_as_float(__builtin_amdgcn_update_dpp(0, __float_as_int(x), 0x118, 0xF, 0xF, true));
    x += __int_as_float(__builtin_amdgcn_update_dpp(0, __float_as_int(x), 0x142, 0xa, 0xF, false));
    x += __int_as_float(__builtin_amdgcn_update_dpp(0, __float_as_int(x), 0x143, 0xc, 0xF, false));
    return x;
}

__device__ __forceinline__ float2 cmulf(float2 a, float2 b) {
    return make_float2(a.x*b.x - a.y*b.y, a.x*b.y + a.y*b.x);
}

// plain 1q gate at position P
template<int P>
__device__ __forceinline__ void apply1q(h2* st, int tid, const h2* m) {
    h2 u00 = m[0], u01 = m[1], u10 = m[2], u11 = m[3];
    if constexpr (P < 3) {
        #pragma unroll
        for (int r = 0; r < NREG; ++r) {
            if ((r >> P) & 1) continue;
            int r1 = r | (1 << P);
            h2 s0 = st[r], s1 = st[r1];
            st[r]  = pk_cmac16(pk_cmul16(u00, s0), u01, s1);
            st[r1] = pk_cmac16(pk_cmul16(u10, s0), u11, s1);
        }
    } else {
        constexpr int LM = 1 << (P - 3);
        int bit = (tid >> (P - 3)) & 1;
        h2 d = bit ? u11 : u00;
        h2 o = bit ? u10 : u01;
        #pragma unroll
        for (int r = 0; r < NREG; ++r) {
            h2 p = lxor_h<LM>(st[r]);
            st[r] = pk_cmac16(pk_cmul16(d, st[r]), o, p);
        }
    }
}

// fused ring1 gate: A (ctrl=0) / B = RX*A (ctrl=1)
template<int PC, int PT>
__device__ __forceinline__ void fgate(h2* st, int tid, const h2* A, const h2* B) {
    h2 a00 = A[0], a01 = A[1], a10 = A[2], a11 = A[3];
    h2 b00 = B[0], b01 = B[1], b10 = B[2], b11 = B[3];
    if constexpr (PT < 3) {
        if constexpr (PC < 3) {
            #pragma unroll
            for (int r = 0; r < NREG; ++r) {
                if ((r >> PT) & 1) continue;
                const bool uB = (r >> PC) & 1;               // compile-time
                h2 m00 = uB ? b00 : a00, m01 = uB ? b01 : a01;
                h2 m10 = uB ? b10 : a10, m11 = uB ? b11 : a11;
                int r1 = r | (1 << PT);
                h2 s0 = st[r], s1 = st[r1];
                st[r]  = pk_cmac16(pk_cmul16(m00, s0), m01, s1);
                st[r1] = pk_cmac16(pk_cmul16(m10, s0), m11, s1);
            }
        } else {
            int cbit = (tid >> (PC - 3)) & 1;
            h2 m00 = cbit ? b00 : a00, m01 = cbit ? b01 : a01;
            h2 m10 = cbit ? b10 : a10, m11 = cbit ? b11 : a11;
            #pragma unroll
            for (int r = 0; r < NREG; ++r) {
                if ((r >> PT) & 1) continue;
                int r1 = r | (1 << PT);
                h2 s0 = st[r], s1 = st[r1];
                st[r]  = pk_cmac16(pk_cmul16(m00, s0), m01, s1);
                st[r1] = pk_cmac16(pk_cmul16(m10, s0), m11, s1);
            }
        }
    } else {
        constexpr int LM = 1 << (PT - 3);
        int tbit = (tid >> (PT - 3)) & 1;
        h2 dA = tbit ? a11 : a00, oA = tbit ? a10 : a01;
        h2 dB = tbit ? b11 : b00, oB = tbit ? b10 : b01;
        if constexpr (PC < 3) {
            #pragma unroll
            for (int r = 0; r < NREG; ++r) {
                const bool uB = (r >> PC) & 1;               // compile-time
                h2 d = uB ? dB : dA, o = uB ? oB : oA;
                h2 p = lxor_h<LM>(st[r]);
                st[r] = pk_cmac16(pk_cmul16(d, st[r]), o, p);
            }
        } else {
            int cbit = (tid >> (PC - 3)) & 1;
            h2 d = cbit ? dB : dA, o = cbit ? oB : oA;
            #pragma unroll
            for (int r = 0; r < NREG; ++r) {
                h2 p = lxor_h<LM>(st[r]);
                st[r] = pk_cmac16(pk_cmul16(d, st[r]), o, p);
            }
        }
    }
}

// CRX(ctrl at PC, tgt at PT)
template<int PC, int PT>
__device__ __forceinline__ void applyCRX(h2* st, int tid, const h2* cs) {
    h2 cs2 = cs[0];                      // packed (cos, sin)
    if constexpr (PT < 3) {
        if constexpr (PC < 3) {
            #pragma unroll
            for (int r = 0; r < NREG; ++r) {
                if (!((r >> PC) & 1) || ((r >> PT) & 1)) continue;
                int r1 = r | (1 << PT);
                h2 s0 = st[r], s1 = st[r1];
                st[r]  = pk_crx16(cs2, s0, s1);
                st[r1] = pk_crx16(cs2, s1, s0);
            }
        } else {
            int apply = (tid >> (PC - 3)) & 1;
            h2 cse = apply ? cs2 : IDH;
            #pragma unroll
            for (int r = 0; r < NREG; ++r) {
                if ((r >> PT) & 1) continue;
                int r1 = r | (1 << PT);
                h2 s0 = st[r], s1 = st[r1];
                st[r]  = pk_crx16(cse, s0, s1);
                st[r1] = pk_crx16(cse, s1, s0);
            }
        }
    } else {
        constexpr int LM = 1 << (PT - 3);
        if constexpr (PC < 3) {
            #pragma unroll
            for (int r = 0; r < NREG; ++r) {
                if (!((r >> PC) & 1)) continue;
                h2 p = lxor_h<LM>(st[r]);
                st[r] = pk_crx16(cs2, st[r], p);
            }
        } else {
            int apply = (tid >> (PC - 3)) & 1;
            h2 cse = apply ? cs2 : IDH;
            #pragma unroll
            for (int r = 0; r < NREG; ++r) {
                h2 p = lxor_h<LM>(st[r]);
                st[r] = pk_crx16(cse, st[r], p);
            }
        }
    }
}

__global__ __launch_bounds__(BLOCK)
void qfe_kernel(const float* __restrict__ params,
                const float* __restrict__ inputs,
                float* __restrict__ out) {
    const int b    = blockIdx.x;
    const int tid  = threadIdx.x;
    const int lane = tid & 63;
    const int w    = tid >> 6;

    __shared__ v2f buf[NREG * BLOCK];      // 32 KB: f16 remaps (16 KB) + f32 epilogue
    h2* bufh = (h2*)buf;
    __shared__ __align__(16) h2 mA[4 * 12 * 4];   // packed f16 matrices
    __shared__ __align__(16) h2 mB[4 * 11 * 4];
    __shared__ __align__(16) h2 mcrx[4 * 24];     // packed (cos,sin)
    __shared__ float  redbuf[8][36];

    if (tid < 48) {
        int l = tid / 12, q = tid % 12;
        const float* pp = params + b * NPARAM + l * 60 + q * 3;
        float ax = pp[0]*0.5f, ay = pp[1]*0.5f, az = pp[2]*0.5f;
        float cx = cosf(ax), sx = sinf(ax);
        float cy = cosf(ay), sy = sinf(ay);
        float cz = cosf(az), sz = sinf(az);
        float2 a00 = make_float2( cy*cx,  sy*sx);
        float2 a01 = make_float2(-sy*cx, -cy*sx);
        float2 a10 = make_float2( sy*cx, -cy*sx);
        float2 a11 = make_float2( cy*cx, -sy*sx);
        float2 e0 = make_float2(cz, -sz);
        float2 e1 = make_float2(cz,  sz);
        float2 u00 = cmulf(e0, a00), u01 = cmulf(e0, a01);
        float2 u10 = cmulf(e1, a10), u11 = cmulf(e1, a11);
        if (l == 0) {   // fold RY input embedding
            float e = inputs[b * NQ + q] * 0.5f;
            float ce = cosf(e), se = sinf(e);
            float2 v00 = make_float2(u00.x*ce + u01.x*se, u00.y*ce + u01.y*se);
            float2 v01 = make_float2(-u00.x*se + u01.x*ce, -u00.y*se + u01.y*ce);
            float2 v10 = make_float2(u10.x*ce + u11.x*se, u10.y*ce + u11.y*se);
            float2 v11 = make_float2(-u10.x*se + u11.x*ce, -u10.y*se + u11.y*ce);
            u00 = v00; u01 = v01; u10 = v10; u11 = v11;
        }
        h2* m = &mA[(l * 12 + q) * 4];
        m[0] = packh2(u00.x, u00.y); m[1] = packh2(u01.x, u01.y);
        m[2] = packh2(u10.x, u10.y); m[3] = packh2(u11.x, u11.y);
    }
    if (tid < 96) {
        int l = tid / 24, k = tid % 24;
        float a = params[b * NPARAM + l * 60 + 36 + k] * 0.5f;
        mcrx[l * 24 + k] = packh2(cosf(a), sinf(a));
    }
    __syncthreads();
    if (tid < 44) {       // B(l,j) = RX(theta_ring1_j) * U(l, j+1)
        int l = tid / 11, j = tid % 11;
        const h2* U = &mA[(l * 12 + (j + 1)) * 4];
        v2f u00 = uph2(U[0]), u01 = uph2(U[1]), u10 = uph2(U[2]), u11 = uph2(U[3]);
        v2f csv = uph2(mcrx[l * 24 + j]);
        float c = csv.x, s = csv.y;
        h2* Bm = &mB[(l * 11 + j) * 4];
        Bm[0] = packh2( c*u00.x + s*u10.y,  c*u00.y - s*u10.x);
        Bm[1] = packh2( c*u01.x + s*u11.y,  c*u01.y - s*u11.x);
        Bm[2] = packh2( s*u00.y + c*u10.x, -s*u00.x + c*u10.y);
        Bm[3] = packh2( s*u01.y + c*u11.x, -s*u01.x + c*u11.y);
    }
    __syncthreads();

    h2 st[NREG];
    #pragma unroll
    for (int r = 0; r < NREG; ++r) st[r] = 0u;
    if (tid == 0) st[0] = IDH;            // |0..0> is map-independent

    const int rb41 = rbase<4,1>(tid);
    const int rb12 = rbase<1,2>(tid);
    const int rb23 = rbase<2,3>(tid);
    const int rb34 = rbase<3,4>(tid);

    #pragma unroll 1
    for (int l = 0; l < 4; ++l) {
        const h2* ma = mA + l * 48;
        const h2* mb = mB + l * 44;
        const h2* cl = mcrx + l * 24;
        // --- block A under M4: q2@0,q1@1,q0@2,q11@3,q4@4,q3@5 ---
        apply1q<2>(st, tid, ma + 0 * 4);                 // U(q0) @2
        fgate<2, 1>(st, tid, ma + 1 * 4, mb + 0 * 4);    // F(0,1): ctrl q0@2, tgt q1@1
        fgate<1, 0>(st, tid, ma + 2 * 4, mb + 1 * 4);    // F(1,2): ctrl q1@1, tgt q2@0
        fgate<0, 5>(st, tid, ma + 3 * 4, mb + 2 * 4);    // F(2,3): ctrl q2@0, tgt q3@5 (bperm)
        fgate<5, 4>(st, tid, ma + 4 * 4, mb + 3 * 4);    // F(3,4): ctrl q3@5, tgt q4@4
        remap<4, 1>(st, tid, bufh, rb41);
        // --- block B under M1: q5@0,q6@1,q7@2,q8@3,q9@4; q4@6 ---
        fgate<6, 0>(st, tid, ma + 5 * 4, mb + 4 * 4);    // F(4,5)
        fgate<0, 1>(st, tid, ma + 6 * 4, mb + 5 * 4);    // F(5,6)
        fgate<1, 2>(st, tid, ma + 7 * 4, mb + 6 * 4);    // F(6,7)
        fgate<2, 3>(st, tid, ma + 8 * 4, mb + 7 * 4);    // F(7,8)
        fgate<3, 4>(st, tid, ma + 9 * 4, mb + 8 * 4);    // F(8,9)
        remap<1, 2>(st, tid, bufh, rb12);
        // --- block C under M2: q10@0,q11@1,q0@2,q9@3,q8@4 ---
        fgate<3, 0>(st, tid, ma + 10 * 4, mb + 9 * 4);   // F(9,10)
        fgate<0, 1>(st, tid, ma + 11 * 4, mb + 10 * 4);  // F(10,11)
        applyCRX<1, 2>(st, tid, cl + 11);                // CRX(11,0)
        applyCRX<1, 0>(st, tid, cl + 12);                // ring2 (11,10)
        applyCRX<0, 3>(st, tid, cl + 13);                // (10,9)
        applyCRX<3, 4>(st, tid, cl + 14);                // (9,8)
        remap<2, 3>(st, tid, bufh, rb23);
        // --- block D under M3: q7@0,q6@1,q5@2,q4@3,q3@4; q8@6 ---
        applyCRX<6, 0>(st, tid, cl + 15);                // (8,7)
        applyCRX<0, 1>(st, tid, cl + 16);                // (7,6)
        applyCRX<1, 2>(st, tid, cl + 17);                // (6,5)
        applyCRX<2, 3>(st, tid, cl + 18);                // (5,4)
        applyCRX<3, 4>(st, tid, cl + 19);                // (4,3)
        remap<3, 4>(st, tid, bufh, rb34);
        // --- block E under M4: q2@0,q1@1,q0@2,q11@3; q3@5 ---
        applyCRX<5, 0>(st, tid, cl + 20);                // (3,2)
        applyCRX<0, 1>(st, tid, cl + 21);                // (2,1)
        applyCRX<1, 2>(st, tid, cl + 22);                // (1,0)
        applyCRX<2, 3>(st, tid, cl + 23);                // (0,11)
        // no remap: next layer's block A runs under M4
    }

    // ---- epilogue (f32) under M4 ----
    // pos->qubit: 0->2, 1->1, 2->0, 3->11, 4->4, 5->3, 6->9, 7->8, 8->10,
    //             9->5, 10->6, 11->7
    v2f stf[NREG];
    #pragma unroll
    for (int r = 0; r < NREG; ++r) stf[r] = uph2(st[r]);

    float nn[NREG];
    #pragma unroll
    for (int r = 0; r < NREG; ++r) nn[r] = stf[r].x*stf[r].x + stf[r].y*stf[r].y;
    float T  = ((nn[0]+nn[1])+(nn[2]+nn[3])) + ((nn[4]+nn[5])+(nn[6]+nn[7]));
    float Z0 = ((nn[0]-nn[1])+(nn[2]-nn[3])) + ((nn[4]-nn[5])+(nn[6]-nn[7]));
    float Z1 = ((nn[0]+nn[1])-(nn[2]+nn[3])) + ((nn[4]+nn[5])-(nn[6]+nn[7]));
    float Z2 = ((nn[0]+nn[1])+(nn[2]+nn[3])) - ((nn[4]+nn[5])+(nn[6]+nn[7]));

    __syncthreads();                       // WAR vs last remap reads
    #pragma unroll
    for (int r = 0; r < NREG; ++r) buf[r * BLOCK + tid] = stf[r];   // f32 layout
    __syncthreads();

#define EXP_REG(q, B, ZV) { \
    v2f acc = {0.f, 0.f}; \
    _Pragma("unroll") \
    for (int r = 0; r < NREG; ++r) { \
        if ((r >> (B)) & 1) continue; \
        acc = pk_cjmac(acc, stf[r], stf[r | (1 << (B))]); \
    } \
    float X = wsum(2.f*acc.x), Y = wsum(2.f*acc.y), Z = wsum(ZV); \
    if (lane == 63) { redbuf[w][(q)] = X; redbuf[w][12+(q)] = Y; redbuf[w][24+(q)] = Z; } }

#define EXP_DPP(q, LM, TB) { \
    v2f acc = {0.f, 0.f}; \
    _Pragma("unroll") \
    for (int r = 0; r < NREG; ++r) { \
        v2f p = lxor2<LM>(stf[r]); \
        acc = pk_cjmac(acc, stf[r], p); \
    } \
    float zs = ((tid >> (TB)) & 1) ? -1.f : 1.f; \
    float X = wsum(acc.x), Y = wsum(zs*acc.y), Z = wsum(zs*T); \
    if (lane == 63) { redbuf[w][(q)] = X; redbuf[w][12+(q)] = Y; redbuf[w][24+(q)] = Z; } }

#define EXP_BUF(q, XM, TB) { \
    v2f acc = {0.f, 0.f}; \
    int pt = tid ^ (XM); \
    _Pragma("unroll") \
    for (int r = 0; r < NREG; ++r) { \
        acc = pk_cjmac(acc, stf[r], buf[r * BLOCK + pt]); \
    } \
    float zs = ((tid >> (TB)) & 1) ? -1.f : 1.f; \
    float X = wsum(acc.x), Y = wsum(zs*acc.y), Z = wsum(zs*T); \
    if (lane == 63) { redbuf[w][(q)] = X; redbuf[w][12+(q)] = Y; redbuf[w][24+(q)] = Z; } }

    EXP_REG(2, 0, Z0)  EXP_REG(1, 1, Z1)  EXP_REG(0, 2, Z2)
    EXP_DPP(11, 1, 0)  EXP_DPP(4, 2, 1)
    EXP_BUF(3, 4, 2)   EXP_BUF(9, 8, 3)   EXP_BUF(8, 16, 4)  EXP_BUF(10, 32, 5)
    EXP_BUF(5, 64, 6)  EXP_BUF(6, 128, 7) EXP_BUF(7, 256, 8)

    __syncthreads();
    if (tid < 36) {
        float acc = 0.f;
        #pragma unroll
        for (int i = 0; i < 8; ++i) acc += redbuf[i][tid];
        out[b * 36 + tid] = acc;
    }
}

extern "C" void kernel_launch(void* const* d_in, const int* in_sizes, int n_in,
                              void* d_out, int out_size, void* d_ws, size_t ws_size,
                              hipStream_t stream) {
    const float* params = (const float*)d_in[0];   // (1024, 240) float32
    const float* inputs = (const float*)d_in[1];   // (1024, 12)  float32
    float* out = (float*)d_out;                    // (1024, 36)  float32
    qfe_kernel<<<1024, BLOCK, 0, stream>>>(params, inputs, out);
}

// Round 14
// 108.589 us; speedup vs baseline: 2.1479x; 1.0116x over previous
//
#include <hip/hip_runtime.h>
#include <hip/hip_fp16.h>

#define NQ     12
#define NPARAM 240       // 12*4*5
#define BLOCK  512
#define NREG   8

typedef float v2f __attribute__((ext_vector_type(2)));
typedef unsigned int h2;     // packed f16 complex: lo=re, hi=im
#define IDH 0x00003C00u      // (1.0, 0.0) in packed f16

// ---- packed f16 complex primitives (v_pk_*_f16, full rate = 2x f32 flops) ----
__device__ __forceinline__ h2 pk_cmul16(h2 a, h2 b) {
    h2 t;
    asm("v_pk_mul_f16 %0, %1, %2 op_sel:[0,0] op_sel_hi:[0,1]\n\t"
        "v_pk_fma_f16 %0, %1, %2, %0 op_sel:[1,1,0] op_sel_hi:[1,0,1] neg_lo:[1,0,0]"
        : "=&v"(t) : "v"(a), "v"(b));
    return t;
}
__device__ __forceinline__ h2 pk_cmac16(h2 t0, h2 a, h2 b) {
    h2 t;
    asm("v_pk_fma_f16 %0, %2, %3, %1 op_sel:[0,0,0] op_sel_hi:[0,1,1]\n\t"
        "v_pk_fma_f16 %0, %2, %3, %0 op_sel:[1,1,0] op_sel_hi:[1,0,1] neg_lo:[1,0,0]"
        : "=&v"(t) : "v"(t0), "v"(a), "v"(b));
    return t;
}
// CRX halfstep: cs2=(c,s): lo = c*sx + s*py ; hi = c*sy - s*px
__device__ __forceinline__ h2 pk_crx16(h2 cs2, h2 s, h2 p) {
    h2 t;
    asm("v_pk_mul_f16 %0, %1, %2 op_sel:[0,0] op_sel_hi:[0,1]\n\t"
        "v_pk_fma_f16 %0, %1, %3, %0 op_sel:[1,1,0] op_sel_hi:[1,0,1] neg_hi:[0,1,0]"
        : "=&v"(t) : "v"(cs2), "v"(s), "v"(p));
    return t;
}
// f32 conj-accumulate for epilogue: acc += conj(s)(.)p
__device__ __forceinline__ v2f pk_cjmac(v2f a0, v2f s, v2f p) {
    v2f t;
    asm("v_pk_fma_f32 %0, %2, %3, %1 op_sel:[0,0,0] op_sel_hi:[0,1,1]\n\t"
        "v_pk_fma_f32 %0, %2, %3, %0 op_sel:[1,1,0] op_sel_hi:[1,0,1] neg_hi:[1,0,0]"
        : "=&v"(t) : "v"(a0), "v"(s), "v"(p));
    return t;
}

__device__ __forceinline__ h2 packh2(float x, float y) {
    return ((h2)__half_as_ushort(__float2half_rn(y)) << 16) |
           (h2)__half_as_ushort(__float2half_rn(x));
}
__device__ __forceinline__ v2f uph2(h2 u) {
    return (v2f){ __half2float(__ushort_as_half((unsigned short)(u & 0xffff))),
                  __half2float(__ushort_as_half((unsigned short)(u >> 16))) };
}

// Storage position p for a qubit:
//   p in [0,3)  -> register bit p of r       : pure VALU
//   p in [3,5)  -> lane bit (p-3), DPP       : pure VALU
//   p in [5,9)  -> lane bit (p-3)            : shfl (bpermute) / buf partner
//   p in [9,12) -> tid bit (p-3) = wave bit  : select-only for ctrl
// 4-map cycle M4 -> M1 -> M2 -> M3 -> M4 (16 remaps). Init/epilogue under M4.
//
// R14: (1) ping-pong remap buffers: buffer k&1's previous readers (remap k-2)
// are ordered before remap k-1's barrier, so the pre-write WAR barrier is
// unnecessary -> 1 barrier per remap (was 2). (2) read address uses base +
// roff (bits provably disjoint) so roff folds into the ds_read immediate.

constexpr int QMAP[5][12] = {
    // pos:   0   1   2   3   4    5   6   7   8    9  10  11
    /*M0*/ {  0,  1,  2,  3,  4,  10, 11,  9,  8,   5,  6,  7},   // unused
    /*M1*/ {  5,  6,  7,  8,  9,   3,  4, 10, 11,   0,  1,  2},
    /*M2*/ { 10, 11,  0,  9,  8,   3,  4,  5,  6,   1,  2,  7},
    /*M3*/ {  7,  6,  5,  4,  3,   9,  8, 10, 11,   0,  1,  2},
    /*M4*/ {  2,  1,  0, 11,  4,   3,  9,  8, 10,   5,  6,  7},
};

constexpr int posof(int m, int q) {
    for (int p = 0; p < 12; ++p) if (QMAP[m][p] == q) return p;
    return -1;
}
constexpr int ebit(int p) { return p < 3 ? 9 + p : p - 3; }
constexpr int roff(int MA, int MB, int r) {
    int off = 0;
    for (int p = 0; p < 3; ++p)
        off |= ((r >> p) & 1) << ebit(posof(MA, QMAP[MB][p]));
    return off;
}

template<int MA, int MB>
__device__ __forceinline__ int rbase(int tid) {
    int base = 0;
    #pragma unroll
    for (int p = 3; p < 12; ++p)
        base |= ((tid >> (p - 3)) & 1) << ebit(posof(MA, QMAP[MB][p]));
    return base;
}

// single-barrier ping-pong remap: PH selects the 16 KB half-buffer
template<int MA, int MB, int PH>
__device__ __forceinline__ void remap(h2* st, int tid, h2* bufh, int base) {
    h2* bp = bufh + PH * (NREG * BLOCK);
    #pragma unroll
    for (int r = 0; r < NREG; ++r) bp[r * BLOCK + tid] = st[r];
    __syncthreads();
    #pragma unroll
    for (int r = 0; r < NREG; ++r) st[r] = bp[base + roff(MA, MB, r)];
}

template<int LM>
__device__ __forceinline__ int lxori(int v) {
    if constexpr (LM == 1) {        // quad_perm [1,0,3,2] = xor 1, VALU pipe
        return __builtin_amdgcn_update_dpp(v, v, 0xB1, 0xF, 0xF, false);
    } else if constexpr (LM == 2) { // quad_perm [2,3,0,1] = xor 2, VALU pipe
        return __builtin_amdgcn_update_dpp(v, v, 0x4E, 0xF, 0xF, false);
    } else {
        return __shfl_xor(v, LM, 64);
    }
}
template<int LM>
__device__ __forceinline__ h2 lxor_h(h2 v) { return (h2)lxori<LM>((int)v); }
template<int LM>
__device__ __forceinline__ v2f lxor2(v2f v) {
    v2f p = { __int_as_float(lxori<LM>(__float_as_int(v.x))),
              __int_as_float(lxori<LM>(__float_as_int(v.y))) };
    return p;
}

// DPP wave-64 sum; total lands in lane 63
__device__ __forceinline__ float wsum(float x) {
    x += __int_as_float(__builtin_amdgcn_update_dpp(0, __float_as_int(x), 0x111, 0xF, 0xF, true));
    x += __int_as_float(__builtin_amdgcn_update_dpp(0, __float_as_int(x), 0x112, 0xF, 0xF, true));
    x += __int_as_float(__builtin_amdgcn_update_dpp(0, __float_as_int(x), 0x114, 0xF, 0xF, true));
    x += __int_as_float(__builtin_amdgcn_update_dpp(0, __float_as_int(x), 0x118, 0xF, 0xF, true));
    x += __int_as_float(__builtin_amdgcn_update_dpp(0, __float_as_int(x), 0x142, 0xa, 0xF, false));
    x += __int_as_float(__builtin_amdgcn_update_dpp(0, __float_as_int(x), 0x143, 0xc, 0xF, false));
    return x;
}

__device__ __forceinline__ float2 cmulf(float2 a, float2 b) {
    return make_float2(a.x*b.x - a.y*b.y, a.x*b.y + a.y*b.x);
}

// plain 1q gate at position P
template<int P>
__device__ __forceinline__ void apply1q(h2* st, int tid, const h2* m) {
    h2 u00 = m[0], u01 = m[1], u10 = m[2], u11 = m[3];
    if constexpr (P < 3) {
        #pragma unroll
        for (int r = 0; r < NREG; ++r) {
            if ((r >> P) & 1) continue;
            int r1 = r | (1 << P);
            h2 s0 = st[r], s1 = st[r1];
            st[r]  = pk_cmac16(pk_cmul16(u00, s0), u01, s1);
            st[r1] = pk_cmac16(pk_cmul16(u10, s0), u11, s1);
        }
    } else {
        constexpr int LM = 1 << (P - 3);
        int bit = (tid >> (P - 3)) & 1;
        h2 d = bit ? u11 : u00;
        h2 o = bit ? u10 : u01;
        #pragma unroll
        for (int r = 0; r < NREG; ++r) {
            h2 p = lxor_h<LM>(st[r]);
            st[r] = pk_cmac16(pk_cmul16(d, st[r]), o, p);
        }
    }
}

// fused ring1 gate: A (ctrl=0) / B = RX*A (ctrl=1)
template<int PC, int PT>
__device__ __forceinline__ void fgate(h2* st, int tid, const h2* A, const h2* B) {
    h2 a00 = A[0], a01 = A[1], a10 = A[2], a11 = A[3];
    h2 b00 = B[0], b01 = B[1], b10 = B[2], b11 = B[3];
    if constexpr (PT < 3) {
        if constexpr (PC < 3) {
            #pragma unroll
            for (int r = 0; r < NREG; ++r) {
                if ((r >> PT) & 1) continue;
                const bool uB = (r >> PC) & 1;               // compile-time
                h2 m00 = uB ? b00 : a00, m01 = uB ? b01 : a01;
                h2 m10 = uB ? b10 : a10, m11 = uB ? b11 : a11;
                int r1 = r | (1 << PT);
                h2 s0 = st[r], s1 = st[r1];
                st[r]  = pk_cmac16(pk_cmul16(m00, s0), m01, s1);
                st[r1] = pk_cmac16(pk_cmul16(m10, s0), m11, s1);
            }
        } else {
            int cbit = (tid >> (PC - 3)) & 1;
            h2 m00 = cbit ? b00 : a00, m01 = cbit ? b01 : a01;
            h2 m10 = cbit ? b10 : a10, m11 = cbit ? b11 : a11;
            #pragma unroll
            for (int r = 0; r < NREG; ++r) {
                if ((r >> PT) & 1) continue;
                int r1 = r | (1 << PT);
                h2 s0 = st[r], s1 = st[r1];
                st[r]  = pk_cmac16(pk_cmul16(m00, s0), m01, s1);
                st[r1] = pk_cmac16(pk_cmul16(m10, s0), m11, s1);
            }
        }
    } else {
        constexpr int LM = 1 << (PT - 3);
        int tbit = (tid >> (PT - 3)) & 1;
        h2 dA = tbit ? a11 : a00, oA = tbit ? a10 : a01;
        h2 dB = tbit ? b11 : b00, oB = tbit ? b10 : b01;
        if constexpr (PC < 3) {
            #pragma unroll
            for (int r = 0; r < NREG; ++r) {
                const bool uB = (r >> PC) & 1;               // compile-time
                h2 d = uB ? dB : dA, o = uB ? oB : oA;
                h2 p = lxor_h<LM>(st[r]);
                st[r] = pk_cmac16(pk_cmul16(d, st[r]), o, p);
            }
        } else {
            int cbit = (tid >> (PC - 3)) & 1;
            h2 d = cbit ? dB : dA, o = cbit ? oB : oA;
            #pragma unroll
            for (int r = 0; r < NREG; ++r) {
                h2 p = lxor_h<LM>(st[r]);
                st[r] = pk_cmac16(pk_cmul16(d, st[r]), o, p);
            }
        }
    }
}

// CRX(ctrl at PC, tgt at PT)
template<int PC, int PT>
__device__ __forceinline__ void applyCRX(h2* st, int tid, const h2* cs) {
    h2 cs2 = cs[0];                      // packed (cos, sin)
    if constexpr (PT < 3) {
        if constexpr (PC < 3) {
            #pragma unroll
            for (int r = 0; r < NREG; ++r) {
                if (!((r >> PC) & 1) || ((r >> PT) & 1)) continue;
                int r1 = r | (1 << PT);
                h2 s0 = st[r], s1 = st[r1];
                st[r]  = pk_crx16(cs2, s0, s1);
                st[r1] = pk_crx16(cs2, s1, s0);
            }
        } else {
            int apply = (tid >> (PC - 3)) & 1;
            h2 cse = apply ? cs2 : IDH;
            #pragma unroll
            for (int r = 0; r < NREG; ++r) {
                if ((r >> PT) & 1) continue;
                int r1 = r | (1 << PT);
                h2 s0 = st[r], s1 = st[r1];
                st[r]  = pk_crx16(cse, s0, s1);
                st[r1] = pk_crx16(cse, s1, s0);
            }
        }
    } else {
        constexpr int LM = 1 << (PT - 3);
        if constexpr (PC < 3) {
            #pragma unroll
            for (int r = 0; r < NREG; ++r) {
                if (!((r >> PC) & 1)) continue;
                h2 p = lxor_h<LM>(st[r]);
                st[r] = pk_crx16(cs2, st[r], p);
            }
        } else {
            int apply = (tid >> (PC - 3)) & 1;
            h2 cse = apply ? cs2 : IDH;
            #pragma unroll
            for (int r = 0; r < NREG; ++r) {
                h2 p = lxor_h<LM>(st[r]);
                st[r] = pk_crx16(cse, st[r], p);
            }
        }
    }
}

__global__ __launch_bounds__(BLOCK)
void qfe_kernel(const float* __restrict__ params,
                const float* __restrict__ inputs,
                float* __restrict__ out) {
    const int b    = blockIdx.x;
    const int tid  = threadIdx.x;
    const int lane = tid & 63;
    const int w    = tid >> 6;

    __shared__ v2f buf[NREG * BLOCK];      // 32 KB: 2x16KB f16 ping-pong / f32 epilogue
    h2* bufh = (h2*)buf;
    __shared__ __align__(16) h2 mA[4 * 12 * 4];   // packed f16 matrices
    __shared__ __align__(16) h2 mB[4 * 11 * 4];
    __shared__ __align__(16) h2 mcrx[4 * 24];     // packed (cos,sin)
    __shared__ float  redbuf[8][36];

    if (tid < 48) {
        int l = tid / 12, q = tid % 12;
        const float* pp = params + b * NPARAM + l * 60 + q * 3;
        float ax = pp[0]*0.5f, ay = pp[1]*0.5f, az = pp[2]*0.5f;
        float cx = cosf(ax), sx = sinf(ax);
        float cy = cosf(ay), sy = sinf(ay);
        float cz = cosf(az), sz = sinf(az);
        float2 a00 = make_float2( cy*cx,  sy*sx);
        float2 a01 = make_float2(-sy*cx, -cy*sx);
        float2 a10 = make_float2( sy*cx, -cy*sx);
        float2 a11 = make_float2( cy*cx, -sy*sx);
        float2 e0 = make_float2(cz, -sz);
        float2 e1 = make_float2(cz,  sz);
        float2 u00 = cmulf(e0, a00), u01 = cmulf(e0, a01);
        float2 u10 = cmulf(e1, a10), u11 = cmulf(e1, a11);
        if (l == 0) {   // fold RY input embedding
            float e = inputs[b * NQ + q] * 0.5f;
            float ce = cosf(e), se = sinf(e);
            float2 v00 = make_float2(u00.x*ce + u01.x*se, u00.y*ce + u01.y*se);
            float2 v01 = make_float2(-u00.x*se + u01.x*ce, -u00.y*se + u01.y*ce);
            float2 v10 = make_float2(u10.x*ce + u11.x*se, u10.y*ce + u11.y*se);
            float2 v11 = make_float2(-u10.x*se + u11.x*ce, -u10.y*se + u11.y*ce);
            u00 = v00; u01 = v01; u10 = v10; u11 = v11;
        }
        h2* m = &mA[(l * 12 + q) * 4];
        m[0] = packh2(u00.x, u00.y); m[1] = packh2(u01.x, u01.y);
        m[2] = packh2(u10.x, u10.y); m[3] = packh2(u11.x, u11.y);
    }
    if (tid < 96) {
        int l = tid / 24, k = tid % 24;
        float a = params[b * NPARAM + l * 60 + 36 + k] * 0.5f;
        mcrx[l * 24 + k] = packh2(cosf(a), sinf(a));
    }
    __syncthreads();
    if (tid < 44) {       // B(l,j) = RX(theta_ring1_j) * U(l, j+1)
        int l = tid / 11, j = tid % 11;
        const h2* U = &mA[(l * 12 + (j + 1)) * 4];
        v2f u00 = uph2(U[0]), u01 = uph2(U[1]), u10 = uph2(U[2]), u11 = uph2(U[3]);
        v2f csv = uph2(mcrx[l * 24 + j]);
        float c = csv.x, s = csv.y;
        h2* Bm = &mB[(l * 11 + j) * 4];
        Bm[0] = packh2( c*u00.x + s*u10.y,  c*u00.y - s*u10.x);
        Bm[1] = packh2( c*u01.x + s*u11.y,  c*u01.y - s*u11.x);
        Bm[2] = packh2( s*u00.y + c*u10.x, -s*u00.x + c*u10.y);
        Bm[3] = packh2( s*u01.y + c*u11.x, -s*u01.x + c*u11.y);
    }
    __syncthreads();

    h2 st[NREG];
    #pragma unroll
    for (int r = 0; r < NREG; ++r) st[r] = 0u;
    if (tid == 0) st[0] = IDH;            // |0..0> is map-independent

    const int rb41 = rbase<4,1>(tid);
    const int rb12 = rbase<1,2>(tid);
    const int rb23 = rbase<2,3>(tid);
    const int rb34 = rbase<3,4>(tid);

    #pragma unroll 1
    for (int l = 0; l < 4; ++l) {
        const h2* ma = mA + l * 48;
        const h2* mb = mB + l * 44;
        const h2* cl = mcrx + l * 24;
        // --- block A under M4: q2@0,q1@1,q0@2,q11@3,q4@4,q3@5 ---
        apply1q<2>(st, tid, ma + 0 * 4);                 // U(q0) @2
        fgate<2, 1>(st, tid, ma + 1 * 4, mb + 0 * 4);    // F(0,1)
        fgate<1, 0>(st, tid, ma + 2 * 4, mb + 1 * 4);    // F(1,2)
        fgate<0, 5>(st, tid, ma + 3 * 4, mb + 2 * 4);    // F(2,3) (bperm)
        fgate<5, 4>(st, tid, ma + 4 * 4, mb + 3 * 4);    // F(3,4)
        remap<4, 1, 0>(st, tid, bufh, rb41);
        // --- block B under M1: q5@0,q6@1,q7@2,q8@3,q9@4; q4@6 ---
        fgate<6, 0>(st, tid, ma + 5 * 4, mb + 4 * 4);    // F(4,5)
        fgate<0, 1>(st, tid, ma + 6 * 4, mb + 5 * 4);    // F(5,6)
        fgate<1, 2>(st, tid, ma + 7 * 4, mb + 6 * 4);    // F(6,7)
        fgate<2, 3>(st, tid, ma + 8 * 4, mb + 7 * 4);    // F(7,8)
        fgate<3, 4>(st, tid, ma + 9 * 4, mb + 8 * 4);    // F(8,9)
        remap<1, 2, 1>(st, tid, bufh, rb12);
        // --- block C under M2: q10@0,q11@1,q0@2,q9@3,q8@4 ---
        fgate<3, 0>(st, tid, ma + 10 * 4, mb + 9 * 4);   // F(9,10)
        fgate<0, 1>(st, tid, ma + 11 * 4, mb + 10 * 4);  // F(10,11)
        applyCRX<1, 2>(st, tid, cl + 11);                // CRX(11,0)
        applyCRX<1, 0>(st, tid, cl + 12);                // ring2 (11,10)
        applyCRX<0, 3>(st, tid, cl + 13);                // (10,9)
        applyCRX<3, 4>(st, tid, cl + 14);                // (9,8)
        remap<2, 3, 0>(st, tid, bufh, rb23);
        // --- block D under M3: q7@0,q6@1,q5@2,q4@3,q3@4; q8@6 ---
        applyCRX<6, 0>(st, tid, cl + 15);                // (8,7)
        applyCRX<0, 1>(st, tid, cl + 16);                // (7,6)
        applyCRX<1, 2>(st, tid, cl + 17);                // (6,5)
        applyCRX<2, 3>(st, tid, cl + 18);                // (5,4)
        applyCRX<3, 4>(st, tid, cl + 19);                // (4,3)
        remap<3, 4, 1>(st, tid, bufh, rb34);
        // --- block E under M4: q2@0,q1@1,q0@2,q11@3; q3@5 ---
        applyCRX<5, 0>(st, tid, cl + 20);                // (3,2)
        applyCRX<0, 1>(st, tid, cl + 21);                // (2,1)
        applyCRX<1, 2>(st, tid, cl + 22);                // (1,0)
        applyCRX<2, 3>(st, tid, cl + 23);                // (0,11)
        // no remap: next layer's block A runs under M4
    }

    // ---- epilogue (f32) under M4 ----
    // pos->qubit: 0->2, 1->1, 2->0, 3->11, 4->4, 5->3, 6->9, 7->8, 8->10,
    //             9->5, 10->6, 11->7
    v2f stf[NREG];
    #pragma unroll
    for (int r = 0; r < NREG; ++r) stf[r] = uph2(st[r]);

    float nn[NREG];
    #pragma unroll
    for (int r = 0; r < NREG; ++r) nn[r] = stf[r].x*stf[r].x + stf[r].y*stf[r].y;
    float T  = ((nn[0]+nn[1])+(nn[2]+nn[3])) + ((nn[4]+nn[5])+(nn[6]+nn[7]));
    float Z0 = ((nn[0]-nn[1])+(nn[2]-nn[3])) + ((nn[4]-nn[5])+(nn[6]-nn[7]));
    float Z1 = ((nn[0]+nn[1])-(nn[2]+nn[3])) + ((nn[4]+nn[5])-(nn[6]+nn[7]));
    float Z2 = ((nn[0]+nn[1])+(nn[2]+nn[3])) - ((nn[4]+nn[5])+(nn[6]+nn[7]));

    __syncthreads();                       // WAR vs last remap reads
    #pragma unroll
    for (int r = 0; r < NREG; ++r) buf[r * BLOCK + tid] = stf[r];   // f32 layout
    __syncthreads();

#define EXP_REG(q, B, ZV) { \
    v2f acc = {0.f, 0.f}; \
    _Pragma("unroll") \
    for (int r = 0; r < NREG; ++r) { \
        if ((r >> (B)) & 1) continue; \
        acc = pk_cjmac(acc, stf[r], stf[r | (1 << (B))]); \
    } \
    float X = wsum(2.f*acc.x), Y = wsum(2.f*acc.y), Z = wsum(ZV); \
    if (lane == 63) { redbuf[w][(q)] = X; redbuf[w][12+(q)] = Y; redbuf[w][24+(q)] = Z; } }

#define EXP_DPP(q, LM, TB) { \
    v2f acc = {0.f, 0.f}; \
    _Pragma("unroll") \
    for (int r = 0; r < NREG; ++r) { \
        v2f p = lxor2<LM>(stf[r]); \
        acc = pk_cjmac(acc, stf[r], p); \
    } \
    float zs = ((tid >> (TB)) & 1) ? -1.f : 1.f; \
    float X = wsum(acc.x), Y = wsum(zs*acc.y), Z = wsum(zs*T); \
    if (lane == 63) { redbuf[w][(q)] = X; redbuf[w][12+(q)] = Y; redbuf[w][24+(q)] = Z; } }

#define EXP_BUF(q, XM, TB) { \
    v2f acc = {0.f, 0.f}; \
    int pt = tid ^ (XM); \
    _Pragma("unroll") \
    for (int r = 0; r < NREG; ++r) { \
        acc = pk_cjmac(acc, stf[r], buf[r * BLOCK + pt]); \
    } \
    float zs = ((tid >> (TB)) & 1) ? -1.f : 1.f; \
    float X = wsum(acc.x), Y = wsum(zs*acc.y), Z = wsum(zs*T); \
    if (lane == 63) { redbuf[w][(q)] = X; redbuf[w][12+(q)] = Y; redbuf[w][24+(q)] = Z; } }

    EXP_REG(2, 0, Z0)  EXP_REG(1, 1, Z1)  EXP_REG(0, 2, Z2)
    EXP_DPP(11, 1, 0)  EXP_DPP(4, 2, 1)
    EXP_BUF(3, 4, 2)   EXP_BUF(9, 8, 3)   EXP_BUF(8, 16, 4)  EXP_BUF(10, 32, 5)
    EXP_BUF(5, 64, 6)  EXP_BUF(6, 128, 7) EXP_BUF(7, 256, 8)

    __syncthreads();
    if (tid < 36) {
        float acc = 0.f;
        #pragma unroll
        for (int i = 0; i < 8; ++i) acc += redbuf[i][tid];
        out[b * 36 + tid] = acc;
    }
}

extern "C" void kernel_launch(void* const* d_in, const int* in_sizes, int n_in,
                              void* d_out, int out_size, void* d_ws, size_t ws_size,
                              hipStream_t stream) {
    const float* params = (const float*)d_in[0];   // (1024, 240) float32
    const float* inputs = (const float*)d_in[1];   // (1024, 12)  float32
    float* out = (float*)d_out;                    // (1024, 36)  float32
    qfe_kernel<<<1024, BLOCK, 0, stream>>>(params, inputs, out);
}